// Round 1
// baseline (762.768 us; speedup 1.0000x reference)
//
#include <hip/hip_runtime.h>
#include <hip/hip_bf16.h>
#include <math.h>

#define B_SZ 1024
#define STOCH 1024
#define ACT 32
#define DETER 4096
#define TOKEN_DIM 512
#define HIDDEN 1024
#define NHEADS 8
#define HEADDIM 128
#define DSTATE 64
#define CONV_DIM 1152
#define IN_PROJ_DIM 2184
#define EPS 0.0001f

// ---------------- GEMM: C = A(MxK) * W(NxK)^T (+bias) (+add) ----------------
#define BM 64
#define BN 64
#define BKK 16

__global__ __launch_bounds__(256) void gemm_nt(
    const float* __restrict__ A,
    const float* __restrict__ W,
    const float* __restrict__ bias,   // N or null
    const float* __restrict__ add,    // MxN or null (residual)
    float* __restrict__ C,
    int M, int N, int K)
{
    __shared__ float As[BKK][BM + 1];
    __shared__ float Ws[BKK][BN + 1];
    int bm = blockIdx.y * BM;
    int bn = blockIdx.x * BN;
    int tid = threadIdx.x;
    int tx = tid & 15;   // n dir
    int ty = tid >> 4;   // m dir
    float acc[4][4] = {{0.f}};

    for (int k0 = 0; k0 < K; k0 += BKK) {
        int row = tid >> 2;        // 0..63
        int kk  = (tid & 3) << 2;  // 0,4,8,12
        {
            const float* src = A + (size_t)(bm + row) * K + k0 + kk;
            float4 v = *(const float4*)src;
            As[kk + 0][row] = v.x; As[kk + 1][row] = v.y;
            As[kk + 2][row] = v.z; As[kk + 3][row] = v.w;
        }
        int nrow = bn + row;
        if (nrow < N) {
            const float* wsrc = W + (size_t)nrow * K + k0 + kk;
            float4 w = *(const float4*)wsrc;
            Ws[kk + 0][row] = w.x; Ws[kk + 1][row] = w.y;
            Ws[kk + 2][row] = w.z; Ws[kk + 3][row] = w.w;
        } else {
            Ws[kk + 0][row] = 0.f; Ws[kk + 1][row] = 0.f;
            Ws[kk + 2][row] = 0.f; Ws[kk + 3][row] = 0.f;
        }
        __syncthreads();
        #pragma unroll
        for (int k = 0; k < BKK; ++k) {
            float a[4], w[4];
            #pragma unroll
            for (int i = 0; i < 4; i++) a[i] = As[k][ty * 4 + i];
            #pragma unroll
            for (int j = 0; j < 4; j++) w[j] = Ws[k][tx * 4 + j];
            #pragma unroll
            for (int i = 0; i < 4; i++)
                #pragma unroll
                for (int j = 0; j < 4; j++)
                    acc[i][j] = fmaf(a[i], w[j], acc[i][j]);
        }
        __syncthreads();
    }

    #pragma unroll
    for (int i = 0; i < 4; i++) {
        int m = bm + ty * 4 + i;
        #pragma unroll
        for (int j = 0; j < 4; j++) {
            int n = bn + tx * 4 + j;
            if (n < N) {
                float v = acc[i][j];
                if (bias) v += bias[n];
                if (add)  v += add[(size_t)m * N + n];
                C[(size_t)m * N + n] = v;
            }
        }
    }
}

// ---------------- rmsnorm (one block per row) ----------------
template<int D, bool SILU>
__global__ __launch_bounds__(256) void rmsnorm_kernel(
    const float* __restrict__ x, const float* __restrict__ w, float* __restrict__ out)
{
    constexpr int VPT = D / 256;
    int b = blockIdx.x;
    const float* row = x + (size_t)b * D;
    float v[VPT];
    float ss = 0.f;
    #pragma unroll
    for (int i = 0; i < VPT; i++) {
        v[i] = row[threadIdx.x + i * 256];
        ss += v[i] * v[i];
    }
    #pragma unroll
    for (int off = 32; off >= 1; off >>= 1) ss += __shfl_xor(ss, off);
    __shared__ float red[4];
    if ((threadIdx.x & 63) == 0) red[threadIdx.x >> 6] = ss;
    __syncthreads();
    float tot = red[0] + red[1] + red[2] + red[3];
    float scale = rsqrtf(tot / (float)D + EPS);
    float* orow = out + (size_t)b * D;
    #pragma unroll
    for (int i = 0; i < VPT; i++) {
        float val = v[i] * scale * w[threadIdx.x + i * 256];
        if (SILU) val = val / (1.f + expf(-val));
        orow[threadIdx.x + i * 256] = val;
    }
}

// gated = rmsnorm(y * silu(z), pw) ; z = proj[:, :HIDDEN]
__global__ __launch_bounds__(256) void gate_rmsnorm_kernel(
    const float* __restrict__ y, const float* __restrict__ proj,
    const float* __restrict__ pw, float* __restrict__ out)
{
    int b = blockIdx.x;
    const float* yr = y + (size_t)b * HIDDEN;
    const float* zr = proj + (size_t)b * IN_PROJ_DIM;
    float v[4];
    float ss = 0.f;
    #pragma unroll
    for (int i = 0; i < 4; i++) {
        int j = threadIdx.x + i * 256;
        float z = zr[j];
        float val = yr[j] * (z / (1.f + expf(-z)));
        v[i] = val;
        ss += val * val;
    }
    #pragma unroll
    for (int off = 32; off >= 1; off >>= 1) ss += __shfl_xor(ss, off);
    __shared__ float red[4];
    if ((threadIdx.x & 63) == 0) red[threadIdx.x >> 6] = ss;
    __syncthreads();
    float tot = red[0] + red[1] + red[2] + red[3];
    float scale = rsqrtf(tot / (float)HIDDEN + EPS);
    float* orow = out + (size_t)b * HIDDEN;
    #pragma unroll
    for (int i = 0; i < 4; i++) {
        int j = threadIdx.x + i * 256;
        orow[j] = v[i] * scale * pw[j];
    }
}

// ---------------- prep input: [stoch | action/max(|a|,1)] ----------------
__global__ __launch_bounds__(256) void prep_inp_kernel(
    const float* __restrict__ stoch, const float* __restrict__ action, float* __restrict__ inp)
{
    int idx = blockIdx.x * 256 + threadIdx.x;
    if (idx >= B_SZ * (STOCH + ACT)) return;
    int b = idx / (STOCH + ACT);
    int j = idx - b * (STOCH + ACT);
    float v;
    if (j < STOCH) {
        v = stoch[(size_t)b * STOCH + j];
    } else {
        float a = action[(size_t)b * ACT + (j - STOCH)];
        float m = fabsf(a);
        v = a / (m > 1.f ? m : 1.f);
    }
    inp[idx] = v;
}

// ---------------- conv step ----------------
__global__ __launch_bounds__(256) void conv_kernel(
    const float* __restrict__ cs,      // B x CONV_DIM x 3
    const float* __restrict__ proj,    // B x IN_PROJ_DIM
    const float* __restrict__ cw,      // CONV_DIM x 4
    const float* __restrict__ cb,      // CONV_DIM
    float* __restrict__ convout,       // B x CONV_DIM
    float* __restrict__ new_cs)        // B x CONV_DIM x 3
{
    int idx = blockIdx.x * 256 + threadIdx.x;
    if (idx >= B_SZ * CONV_DIM) return;
    int b = idx / CONV_DIM;
    int c = idx - b * CONV_DIM;
    const float* s = cs + ((size_t)b * CONV_DIM + c) * 3;
    float s0 = s[0], s1 = s[1], s2 = s[2];
    float xbc = proj[(size_t)b * IN_PROJ_DIM + HIDDEN + c];
    const float* wv = cw + c * 4;
    float v = wv[0] * s0 + wv[1] * s1 + wv[2] * s2 + wv[3] * xbc + cb[c];
    v = v / (1.f + expf(-v));
    convout[idx] = v;
    float* nc = new_cs + ((size_t)b * CONV_DIM + c) * 3;
    nc[0] = s1; nc[1] = s2; nc[2] = xbc;
}

// ---------------- SSM state update ----------------
__global__ __launch_bounds__(256) void ssm_kernel(
    const float* __restrict__ ss,    // B x NHEADS x HEADDIM x DSTATE
    const float* __restrict__ conv,  // B x CONV_DIM
    const float* __restrict__ proj,  // B x IN_PROJ_DIM
    const float* __restrict__ dtb,   // NHEADS
    const float* __restrict__ alog,  // NHEADS
    const float* __restrict__ Dv,    // NHEADS
    float* __restrict__ new_ss,      // out
    float* __restrict__ y)           // B x HIDDEN
{
    int b = blockIdx.x >> 3;
    int h = blockIdx.x & 7;
    int tid = threadIdx.x;

    float dtr = proj[(size_t)b * IN_PROJ_DIM + HIDDEN + CONV_DIM + h] + dtb[h];
    float dt = dtr > 20.f ? dtr : log1pf(expf(dtr));
    float dA = expf(dt * -expf(alog[h]));
    float Dk = Dv[h];

    __shared__ float Bs[DSTATE], Cs[DSTATE];
    if (tid < DSTATE) Bs[tid] = conv[(size_t)b * CONV_DIM + HIDDEN + tid];
    else if (tid < 2 * DSTATE) Cs[tid - DSTATE] = conv[(size_t)b * CONV_DIM + HIDDEN + DSTATE + (tid - DSTATE)];
    __syncthreads();

    int p = tid >> 1;
    int n0 = (tid & 1) * 32;
    float xp = conv[(size_t)b * CONV_DIM + h * HEADDIM + p];
    float dtx = dt * xp;

    const float* sp = ss + (((size_t)b * NHEADS + h) * HEADDIM + p) * DSTATE + n0;
    float* op = new_ss + (((size_t)b * NHEADS + h) * HEADDIM + p) * DSTATE + n0;

    float acc = 0.f;
    #pragma unroll
    for (int n = 0; n < 32; n += 4) {
        float4 s4 = *(const float4*)(sp + n);
        float4 o;
        o.x = fmaf(s4.x, dA, dtx * Bs[n0 + n + 0]);
        o.y = fmaf(s4.y, dA, dtx * Bs[n0 + n + 1]);
        o.z = fmaf(s4.z, dA, dtx * Bs[n0 + n + 2]);
        o.w = fmaf(s4.w, dA, dtx * Bs[n0 + n + 3]);
        acc = fmaf(o.x, Cs[n0 + n + 0], acc);
        acc = fmaf(o.y, Cs[n0 + n + 1], acc);
        acc = fmaf(o.z, Cs[n0 + n + 2], acc);
        acc = fmaf(o.w, Cs[n0 + n + 3], acc);
        *(float4*)(op + n) = o;
    }
    acc += __shfl_xor(acc, 1);
    if ((tid & 1) == 0) {
        y[(size_t)b * HIDDEN + h * HEADDIM + p] = acc + Dk * xp;
    }
}

// ---------------- final tape shift ----------------
__global__ __launch_bounds__(256) void write_deter_kernel(
    const float* __restrict__ deter, const float* __restrict__ xt, float* __restrict__ out)
{
    int idx = blockIdx.x * 256 + threadIdx.x;  // over B_SZ*1024 float4 slots
    int b = idx >> 10;
    int j4 = idx & 1023;
    float4 v;
    if (j4 < 896) v = *(const float4*)(deter + (size_t)b * DETER + 512 + j4 * 4);
    else          v = *(const float4*)(xt + (size_t)b * TOKEN_DIM + (j4 - 896) * 4);
    *(float4*)(out + (size_t)b * DETER + j4 * 4) = v;
}

// ---------------- launch ----------------
extern "C" void kernel_launch(void* const* d_in, const int* in_sizes, int n_in,
                              void* d_out, int out_size, void* d_ws, size_t ws_size,
                              hipStream_t stream) {
    const float* stoch      = (const float*)d_in[0];
    const float* deter      = (const float*)d_in[1];
    const float* action     = (const float*)d_in[2];
    const float* conv_state = (const float*)d_in[3];
    const float* ssm_state  = (const float*)d_in[4];
    const float* in_proj_w  = (const float*)d_in[5];
    const float* in_proj_b  = (const float*)d_in[6];
    const float* in_norm_w  = (const float*)d_in[7];
    const float* blk_norm_w = (const float*)d_in[8];
    const float* blk_in_w   = (const float*)d_in[9];
    const float* blk_conv_w = (const float*)d_in[10];
    const float* blk_conv_b = (const float*)d_in[11];
    const float* blk_A_log  = (const float*)d_in[12];
    const float* blk_D      = (const float*)d_in[13];
    const float* blk_dt_bias= (const float*)d_in[14];
    const float* blk_post_norm_w = (const float*)d_in[15];
    const float* blk_out_w  = (const float*)d_in[16];
    const float* blk_out_b  = (const float*)d_in[17];
    const float* out_norm_w = (const float*)d_in[18];

    float* out_deter = (float*)d_out;                       // 1024*4096
    float* out_cs    = out_deter + (size_t)B_SZ * DETER;    // 2*1024*1152*3
    float* out_ss    = out_cs + (size_t)2 * B_SZ * CONV_DIM * 3; // 2*1024*8*128*64

    float* ws = (float*)d_ws;
    float* X     = ws;                         // 1024*512
    float* H     = X + (size_t)B_SZ * TOKEN_DIM;       // 1024*512
    float* PROJ  = H + (size_t)B_SZ * TOKEN_DIM;       // 1024*2184
    float* CONV  = PROJ + (size_t)B_SZ * IN_PROJ_DIM;  // 1024*1152
    float* Y     = CONV + (size_t)B_SZ * CONV_DIM;     // 1024*1024
    float* GATED = Y + (size_t)B_SZ * HIDDEN;          // 1024*1024
    float* INP   = PROJ;  // reuse (1024*1056 <= 1024*2184), used before PROJ

    // 1. inp = [stoch | action/max(|a|,1)]
    {
        int n = B_SZ * (STOCH + ACT);
        prep_inp_kernel<<<(n + 255) / 256, 256, 0, stream>>>(stoch, action, INP);
    }
    // 2. H = inp @ in_proj_w.T + b ; X = silu(rmsnorm(H))
    {
        dim3 grid((TOKEN_DIM + BN - 1) / BN, B_SZ / BM);
        gemm_nt<<<grid, 256, 0, stream>>>(INP, in_proj_w, in_proj_b, nullptr, H,
                                          B_SZ, TOKEN_DIM, STOCH + ACT);
        rmsnorm_kernel<TOKEN_DIM, true><<<B_SZ, 256, 0, stream>>>(H, in_norm_w, X);
    }

    for (int l = 0; l < 2; ++l) {
        const float* nw  = blk_norm_w + (size_t)l * TOKEN_DIM;
        const float* iw  = blk_in_w + (size_t)l * IN_PROJ_DIM * TOKEN_DIM;
        const float* cw  = blk_conv_w + (size_t)l * CONV_DIM * 4;
        const float* cb  = blk_conv_b + (size_t)l * CONV_DIM;
        const float* alog= blk_A_log + (size_t)l * NHEADS;
        const float* Dv  = blk_D + (size_t)l * NHEADS;
        const float* dtb = blk_dt_bias + (size_t)l * NHEADS;
        const float* pw  = blk_post_norm_w + (size_t)l * HIDDEN;
        const float* ow  = blk_out_w + (size_t)l * TOKEN_DIM * HIDDEN;
        const float* ob  = blk_out_b + (size_t)l * TOKEN_DIM;
        const float* cs_in = conv_state + (size_t)l * B_SZ * CONV_DIM * 3;
        const float* ss_in = ssm_state + (size_t)l * B_SZ * NHEADS * HEADDIM * DSTATE;
        float* cs_out = out_cs + (size_t)l * B_SZ * CONV_DIM * 3;
        float* ss_out = out_ss + (size_t)l * B_SZ * NHEADS * HEADDIM * DSTATE;

        // a. H = rmsnorm(X)
        rmsnorm_kernel<TOKEN_DIM, false><<<B_SZ, 256, 0, stream>>>(X, nw, H);
        // b. PROJ = H @ iw.T
        {
            dim3 grid((IN_PROJ_DIM + BN - 1) / BN, B_SZ / BM);
            gemm_nt<<<grid, 256, 0, stream>>>(H, iw, nullptr, nullptr, PROJ,
                                              B_SZ, IN_PROJ_DIM, TOKEN_DIM);
        }
        // c. conv
        {
            int n = B_SZ * CONV_DIM;
            conv_kernel<<<(n + 255) / 256, 256, 0, stream>>>(cs_in, PROJ, cw, cb, CONV, cs_out);
        }
        // d. ssm
        ssm_kernel<<<B_SZ * NHEADS, 256, 0, stream>>>(ss_in, CONV, PROJ, dtb, alog, Dv, ss_out, Y);
        // e. gated = rmsnorm(Y * silu(z))
        gate_rmsnorm_kernel<<<B_SZ, 256, 0, stream>>>(Y, PROJ, pw, GATED);
        // f. X = X + gated @ ow.T + ob
        {
            dim3 grid((TOKEN_DIM + BN - 1) / BN, B_SZ / BM);
            gemm_nt<<<grid, 256, 0, stream>>>(GATED, ow, ob, X, X,
                                              B_SZ, TOKEN_DIM, HIDDEN);
        }
    }

    // final: H = rmsnorm(X, out_norm_w); tape shift
    rmsnorm_kernel<TOKEN_DIM, false><<<B_SZ, 256, 0, stream>>>(X, out_norm_w, H);
    write_deter_kernel<<<(B_SZ * 1024) / 256, 256, 0, stream>>>(deter, H, out_deter);
}

// Round 2
// 458.608 us; speedup vs baseline: 1.6632x; 1.6632x over previous
//
#include <hip/hip_runtime.h>
#include <hip/hip_bf16.h>
#include <math.h>

#define B_SZ 1024
#define STOCH 1024
#define ACT 32
#define DETER 4096
#define TOKEN_DIM 512
#define HIDDEN 1024
#define NHEADS 8
#define HEADDIM 128
#define DSTATE 64
#define CONV_DIM 1152
#define IN_PROJ_DIM 2184
#define EPS 0.0001f

typedef float f32x4 __attribute__((ext_vector_type(4)));
typedef __bf16 bf16x8 __attribute__((ext_vector_type(8)));
typedef __bf16 bf16x4 __attribute__((ext_vector_type(4)));

// ---------------- f32 -> bf16 conversion (weights) ----------------
__global__ __launch_bounds__(256) void cvt_f32_bf16(
    const float* __restrict__ in, __bf16* __restrict__ out, int n4)
{
    int i = blockIdx.x * 256 + threadIdx.x;
    if (i >= n4) return;
    float4 v = ((const float4*)in)[i];
    bf16x4 o = { (__bf16)v.x, (__bf16)v.y, (__bf16)v.z, (__bf16)v.w };
    ((bf16x4*)out)[i] = o;
}

// ---------------- MFMA GEMM: C(f32) = A_bf16(MxK) @ W_bf16(NxK)^T ----------------
#define GBM 64
#define GBN 64
#define GBK 32
#define LDP 40   // padded LDS row (bf16 units): 32 + 8

__global__ __launch_bounds__(256) void gemm_bf16(
    const __bf16* __restrict__ A,
    const __bf16* __restrict__ W,
    const float* __restrict__ bias,  // N or null
    const float* __restrict__ add,   // MxN or null
    float* __restrict__ C,
    int M, int N, int K)
{
    __shared__ __bf16 As[GBM][LDP];
    __shared__ __bf16 Ws[GBN][LDP];
    int bm = blockIdx.y * GBM;
    int bn = blockIdx.x * GBN;
    int tid = threadIdx.x;
    int wid = tid >> 6;
    int lane = tid & 63;
    int wm = (wid >> 1) * 32;
    int wn = (wid & 1) * 32;

    int lrow = tid >> 2;       // 0..63 staging row
    int lk   = (tid & 3) * 8;  // 0,8,16,24

    f32x4 acc[2][2] = {};
    int arow_g = bm + lrow;    // M = 1024, always valid
    int wrow_g = bn + lrow;    // may exceed N

    int r = lane & 15;
    int kgrp = (lane >> 4) * 8;

    for (int k0 = 0; k0 < K; k0 += GBK) {
        bf16x8 av = *(const bf16x8*)(A + (size_t)arow_g * K + k0 + lk);
        bf16x8 wv = {};
        if (wrow_g < N) wv = *(const bf16x8*)(W + (size_t)wrow_g * K + k0 + lk);
        *(bf16x8*)(&As[lrow][lk]) = av;
        *(bf16x8*)(&Ws[lrow][lk]) = wv;
        __syncthreads();

        bf16x8 a0 = *(const bf16x8*)(&As[wm + r][kgrp]);
        bf16x8 a1 = *(const bf16x8*)(&As[wm + 16 + r][kgrp]);
        bf16x8 b0 = *(const bf16x8*)(&Ws[wn + r][kgrp]);
        bf16x8 b1 = *(const bf16x8*)(&Ws[wn + 16 + r][kgrp]);
        acc[0][0] = __builtin_amdgcn_mfma_f32_16x16x32_bf16(a0, b0, acc[0][0], 0, 0, 0);
        acc[0][1] = __builtin_amdgcn_mfma_f32_16x16x32_bf16(a0, b1, acc[0][1], 0, 0, 0);
        acc[1][0] = __builtin_amdgcn_mfma_f32_16x16x32_bf16(a1, b0, acc[1][0], 0, 0, 0);
        acc[1][1] = __builtin_amdgcn_mfma_f32_16x16x32_bf16(a1, b1, acc[1][1], 0, 0, 0);
        __syncthreads();
    }

    int cr = (lane >> 4) * 4;
    int cc = lane & 15;
    #pragma unroll
    for (int mi = 0; mi < 2; mi++) {
        #pragma unroll
        for (int ni = 0; ni < 2; ni++) {
            int n = bn + wn + ni * 16 + cc;
            if (n >= N) continue;
            #pragma unroll
            for (int j = 0; j < 4; j++) {
                int m = bm + wm + mi * 16 + cr + j;
                float v = acc[mi][ni][j];
                if (bias) v += bias[n];
                if (add)  v += add[(size_t)m * N + n];
                C[(size_t)m * N + n] = v;
            }
        }
    }
}

// ---------------- rmsnorm (one block per row) ----------------
template<int D, bool SILU, typename OutT>
__global__ __launch_bounds__(256) void rmsnorm_kernel(
    const float* __restrict__ x, const float* __restrict__ w, OutT* __restrict__ out)
{
    constexpr int VPT = D / 256;
    int b = blockIdx.x;
    const float* row = x + (size_t)b * D;
    float v[VPT];
    float ss = 0.f;
    #pragma unroll
    for (int i = 0; i < VPT; i++) {
        v[i] = row[threadIdx.x + i * 256];
        ss += v[i] * v[i];
    }
    #pragma unroll
    for (int off = 32; off >= 1; off >>= 1) ss += __shfl_xor(ss, off);
    __shared__ float red[4];
    if ((threadIdx.x & 63) == 0) red[threadIdx.x >> 6] = ss;
    __syncthreads();
    float tot = red[0] + red[1] + red[2] + red[3];
    float scale = rsqrtf(tot / (float)D + EPS);
    OutT* orow = out + (size_t)b * D;
    #pragma unroll
    for (int i = 0; i < VPT; i++) {
        float val = v[i] * scale * w[threadIdx.x + i * 256];
        if (SILU) val = val / (1.f + expf(-val));
        orow[threadIdx.x + i * 256] = (OutT)val;
    }
}

// gated = rmsnorm(y * silu(z), pw) -> bf16 ; z = proj[:, :HIDDEN]
__global__ __launch_bounds__(256) void gate_rmsnorm_kernel(
    const float* __restrict__ y, const float* __restrict__ proj,
    const float* __restrict__ pw, __bf16* __restrict__ out)
{
    int b = blockIdx.x;
    const float* yr = y + (size_t)b * HIDDEN;
    const float* zr = proj + (size_t)b * IN_PROJ_DIM;
    float v[4];
    float ss = 0.f;
    #pragma unroll
    for (int i = 0; i < 4; i++) {
        int j = threadIdx.x + i * 256;
        float z = zr[j];
        float val = yr[j] * (z / (1.f + expf(-z)));
        v[i] = val;
        ss += val * val;
    }
    #pragma unroll
    for (int off = 32; off >= 1; off >>= 1) ss += __shfl_xor(ss, off);
    __shared__ float red[4];
    if ((threadIdx.x & 63) == 0) red[threadIdx.x >> 6] = ss;
    __syncthreads();
    float tot = red[0] + red[1] + red[2] + red[3];
    float scale = rsqrtf(tot / (float)HIDDEN + EPS);
    __bf16* orow = out + (size_t)b * HIDDEN;
    #pragma unroll
    for (int i = 0; i < 4; i++) {
        int j = threadIdx.x + i * 256;
        orow[j] = (__bf16)(v[i] * scale * pw[j]);
    }
}

// ---------------- prep input: [stoch | action/max(|a|,1)] -> bf16 ----------------
__global__ __launch_bounds__(256) void prep_inp_kernel(
    const float* __restrict__ stoch, const float* __restrict__ action, __bf16* __restrict__ inp)
{
    int idx = blockIdx.x * 256 + threadIdx.x;
    if (idx >= B_SZ * (STOCH + ACT)) return;
    int b = idx / (STOCH + ACT);
    int j = idx - b * (STOCH + ACT);
    float v;
    if (j < STOCH) {
        v = stoch[(size_t)b * STOCH + j];
    } else {
        float a = action[(size_t)b * ACT + (j - STOCH)];
        float m = fabsf(a);
        v = a / (m > 1.f ? m : 1.f);
    }
    inp[idx] = (__bf16)v;
}

// ---------------- conv step ----------------
__global__ __launch_bounds__(256) void conv_kernel(
    const float* __restrict__ cs,      // B x CONV_DIM x 3
    const float* __restrict__ proj,    // B x IN_PROJ_DIM
    const float* __restrict__ cw,      // CONV_DIM x 4
    const float* __restrict__ cb,      // CONV_DIM
    float* __restrict__ convout,       // B x CONV_DIM
    float* __restrict__ new_cs)        // B x CONV_DIM x 3
{
    int idx = blockIdx.x * 256 + threadIdx.x;
    if (idx >= B_SZ * CONV_DIM) return;
    int b = idx / CONV_DIM;
    int c = idx - b * CONV_DIM;
    const float* s = cs + ((size_t)b * CONV_DIM + c) * 3;
    float s0 = s[0], s1 = s[1], s2 = s[2];
    float xbc = proj[(size_t)b * IN_PROJ_DIM + HIDDEN + c];
    const float* wv = cw + c * 4;
    float v = wv[0] * s0 + wv[1] * s1 + wv[2] * s2 + wv[3] * xbc + cb[c];
    v = v / (1.f + expf(-v));
    convout[idx] = v;
    float* nc = new_cs + ((size_t)b * CONV_DIM + c) * 3;
    nc[0] = s1; nc[1] = s2; nc[2] = xbc;
}

// ---------------- SSM state update ----------------
__global__ __launch_bounds__(256) void ssm_kernel(
    const float* __restrict__ ss,    // B x NHEADS x HEADDIM x DSTATE
    const float* __restrict__ conv,  // B x CONV_DIM
    const float* __restrict__ proj,  // B x IN_PROJ_DIM
    const float* __restrict__ dtb,   // NHEADS
    const float* __restrict__ alog,  // NHEADS
    const float* __restrict__ Dv,    // NHEADS
    float* __restrict__ new_ss,      // out
    float* __restrict__ y)           // B x HIDDEN
{
    int b = blockIdx.x >> 3;
    int h = blockIdx.x & 7;
    int tid = threadIdx.x;

    float dtr = proj[(size_t)b * IN_PROJ_DIM + HIDDEN + CONV_DIM + h] + dtb[h];
    float dt = dtr > 20.f ? dtr : log1pf(expf(dtr));
    float dA = expf(dt * -expf(alog[h]));
    float Dk = Dv[h];

    __shared__ float Bs[DSTATE], Cs[DSTATE];
    if (tid < DSTATE) Bs[tid] = conv[(size_t)b * CONV_DIM + HIDDEN + tid];
    else if (tid < 2 * DSTATE) Cs[tid - DSTATE] = conv[(size_t)b * CONV_DIM + HIDDEN + DSTATE + (tid - DSTATE)];
    __syncthreads();

    int p = tid >> 1;
    int n0 = (tid & 1) * 32;
    float xp = conv[(size_t)b * CONV_DIM + h * HEADDIM + p];
    float dtx = dt * xp;

    const float* sp = ss + (((size_t)b * NHEADS + h) * HEADDIM + p) * DSTATE + n0;
    float* op = new_ss + (((size_t)b * NHEADS + h) * HEADDIM + p) * DSTATE + n0;

    float acc = 0.f;
    #pragma unroll
    for (int n = 0; n < 32; n += 4) {
        float4 s4 = *(const float4*)(sp + n);
        float4 o;
        o.x = fmaf(s4.x, dA, dtx * Bs[n0 + n + 0]);
        o.y = fmaf(s4.y, dA, dtx * Bs[n0 + n + 1]);
        o.z = fmaf(s4.z, dA, dtx * Bs[n0 + n + 2]);
        o.w = fmaf(s4.w, dA, dtx * Bs[n0 + n + 3]);
        acc = fmaf(o.x, Cs[n0 + n + 0], acc);
        acc = fmaf(o.y, Cs[n0 + n + 1], acc);
        acc = fmaf(o.z, Cs[n0 + n + 2], acc);
        acc = fmaf(o.w, Cs[n0 + n + 3], acc);
        *(float4*)(op + n) = o;
    }
    acc += __shfl_xor(acc, 1);
    if ((tid & 1) == 0) {
        y[(size_t)b * HIDDEN + h * HEADDIM + p] = acc + Dk * xp;
    }
}

// ---------------- final tape shift ----------------
__global__ __launch_bounds__(256) void write_deter_kernel(
    const float* __restrict__ deter, const float* __restrict__ xt, float* __restrict__ out)
{
    int idx = blockIdx.x * 256 + threadIdx.x;
    int b = idx >> 10;
    int j4 = idx & 1023;
    float4 v;
    if (j4 < 896) v = *(const float4*)(deter + (size_t)b * DETER + 512 + j4 * 4);
    else          v = *(const float4*)(xt + (size_t)b * TOKEN_DIM + (j4 - 896) * 4);
    *(float4*)(out + (size_t)b * DETER + j4 * 4) = v;
}

// ---------------- launch ----------------
extern "C" void kernel_launch(void* const* d_in, const int* in_sizes, int n_in,
                              void* d_out, int out_size, void* d_ws, size_t ws_size,
                              hipStream_t stream) {
    const float* stoch      = (const float*)d_in[0];
    const float* deter      = (const float*)d_in[1];
    const float* action     = (const float*)d_in[2];
    const float* conv_state = (const float*)d_in[3];
    const float* ssm_state  = (const float*)d_in[4];
    const float* in_proj_w  = (const float*)d_in[5];
    const float* in_proj_b  = (const float*)d_in[6];
    const float* in_norm_w  = (const float*)d_in[7];
    const float* blk_norm_w = (const float*)d_in[8];
    const float* blk_in_w   = (const float*)d_in[9];
    const float* blk_conv_w = (const float*)d_in[10];
    const float* blk_conv_b = (const float*)d_in[11];
    const float* blk_A_log  = (const float*)d_in[12];
    const float* blk_D      = (const float*)d_in[13];
    const float* blk_dt_bias= (const float*)d_in[14];
    const float* blk_post_norm_w = (const float*)d_in[15];
    const float* blk_out_w  = (const float*)d_in[16];
    const float* blk_out_b  = (const float*)d_in[17];
    const float* out_norm_w = (const float*)d_in[18];

    float* out_deter = (float*)d_out;
    float* out_cs    = out_deter + (size_t)B_SZ * DETER;
    float* out_ss    = out_cs + (size_t)2 * B_SZ * CONV_DIM * 3;

    // workspace layout (bytes)
    char* ws = (char*)d_ws;
    __bf16* Wb_inproj = (__bf16*)ws;                 ws += (size_t)TOKEN_DIM * (STOCH + ACT) * 2;       // 1.08 MB
    __bf16* Wb_blkin  = (__bf16*)ws;                 ws += (size_t)2 * IN_PROJ_DIM * TOKEN_DIM * 2;     // 4.47 MB
    __bf16* Wb_blkout = (__bf16*)ws;                 ws += (size_t)2 * TOKEN_DIM * HIDDEN * 2;          // 2.10 MB
    float*  X         = (float*)ws;                  ws += (size_t)B_SZ * TOKEN_DIM * 4;                // 2.10 MB
    __bf16* Hb        = (__bf16*)ws;                 ws += (size_t)B_SZ * TOKEN_DIM * 2;                // 1.05 MB
    float*  PROJ      = (float*)ws;                  ws += (size_t)B_SZ * IN_PROJ_DIM * 4;              // 8.95 MB
    float*  CONV      = (float*)ws;                  ws += (size_t)B_SZ * CONV_DIM * 4;                 // 4.72 MB
    float*  Y         = (float*)ws;                  ws += (size_t)B_SZ * HIDDEN * 4;                   // 4.19 MB
    __bf16* Gb        = (__bf16*)ws;                 ws += (size_t)B_SZ * HIDDEN * 2;                   // 2.10 MB
    __bf16* INPb = (__bf16*)Y;       // alias: INP used only before first ssm writes Y
    float*  XT   = CONV;             // alias: final rmsnorm output, CONV dead by then

    // 0. convert weights to bf16
    {
        int n4 = TOKEN_DIM * (STOCH + ACT) / 4;
        cvt_f32_bf16<<<(n4 + 255) / 256, 256, 0, stream>>>(in_proj_w, Wb_inproj, n4);
        n4 = 2 * IN_PROJ_DIM * TOKEN_DIM / 4;
        cvt_f32_bf16<<<(n4 + 255) / 256, 256, 0, stream>>>(blk_in_w, Wb_blkin, n4);
        n4 = 2 * TOKEN_DIM * HIDDEN / 4;
        cvt_f32_bf16<<<(n4 + 255) / 256, 256, 0, stream>>>(blk_out_w, Wb_blkout, n4);
    }

    // 1. inp = [stoch | action/max(|a|,1)] (bf16)
    {
        int n = B_SZ * (STOCH + ACT);
        prep_inp_kernel<<<(n + 255) / 256, 256, 0, stream>>>(stoch, action, INPb);
    }
    // 2. PROJ[:, :512] = inp @ in_proj_w.T + b ; X = silu(rmsnorm(.))
    {
        dim3 grid(TOKEN_DIM / GBN, B_SZ / GBM);
        gemm_bf16<<<grid, 256, 0, stream>>>(INPb, Wb_inproj, in_proj_b, nullptr, PROJ,
                                            B_SZ, TOKEN_DIM, STOCH + ACT);
        rmsnorm_kernel<TOKEN_DIM, true, float><<<B_SZ, 256, 0, stream>>>(PROJ, in_norm_w, X);
    }

    for (int l = 0; l < 2; ++l) {
        const float* nw  = blk_norm_w + (size_t)l * TOKEN_DIM;
        const __bf16* iw = Wb_blkin + (size_t)l * IN_PROJ_DIM * TOKEN_DIM;
        const float* cw  = blk_conv_w + (size_t)l * CONV_DIM * 4;
        const float* cb  = blk_conv_b + (size_t)l * CONV_DIM;
        const float* alog= blk_A_log + (size_t)l * NHEADS;
        const float* Dv  = blk_D + (size_t)l * NHEADS;
        const float* dtb = blk_dt_bias + (size_t)l * NHEADS;
        const float* pw  = blk_post_norm_w + (size_t)l * HIDDEN;
        const __bf16* ow = Wb_blkout + (size_t)l * TOKEN_DIM * HIDDEN;
        const float* ob  = blk_out_b + (size_t)l * TOKEN_DIM;
        const float* cs_in = conv_state + (size_t)l * B_SZ * CONV_DIM * 3;
        const float* ss_in = ssm_state + (size_t)l * B_SZ * NHEADS * HEADDIM * DSTATE;
        float* cs_out = out_cs + (size_t)l * B_SZ * CONV_DIM * 3;
        float* ss_out = out_ss + (size_t)l * B_SZ * NHEADS * HEADDIM * DSTATE;

        // a. Hb = rmsnorm(X) (bf16)
        rmsnorm_kernel<TOKEN_DIM, false, __bf16><<<B_SZ, 256, 0, stream>>>(X, nw, Hb);
        // b. PROJ = Hb @ iw.T
        {
            dim3 grid((IN_PROJ_DIM + GBN - 1) / GBN, B_SZ / GBM);
            gemm_bf16<<<grid, 256, 0, stream>>>(Hb, iw, nullptr, nullptr, PROJ,
                                                B_SZ, IN_PROJ_DIM, TOKEN_DIM);
        }
        // c. conv
        {
            int n = B_SZ * CONV_DIM;
            conv_kernel<<<(n + 255) / 256, 256, 0, stream>>>(cs_in, PROJ, cw, cb, CONV, cs_out);
        }
        // d. ssm
        ssm_kernel<<<B_SZ * NHEADS, 256, 0, stream>>>(ss_in, CONV, PROJ, dtb, alog, Dv, ss_out, Y);
        // e. Gb = rmsnorm(Y * silu(z)) (bf16)
        gate_rmsnorm_kernel<<<B_SZ, 256, 0, stream>>>(Y, PROJ, pw, Gb);
        // f. X = X + Gb @ ow.T + ob
        {
            dim3 grid(TOKEN_DIM / GBN, B_SZ / GBM);
            gemm_bf16<<<grid, 256, 0, stream>>>(Gb, ow, ob, X, X,
                                                B_SZ, TOKEN_DIM, HIDDEN);
        }
    }

    // final: XT = rmsnorm(X, out_norm_w); tape shift
    rmsnorm_kernel<TOKEN_DIM, false, float><<<B_SZ, 256, 0, stream>>>(X, out_norm_w, XT);
    write_deter_kernel<<<(B_SZ * 1024) / 256, 256, 0, stream>>>(deter, XT, out_deter);
}

// Round 3
// 330.779 us; speedup vs baseline: 2.3060x; 1.3864x over previous
//
#include <hip/hip_runtime.h>
#include <hip/hip_bf16.h>
#include <math.h>

#define B_SZ 1024
#define STOCH 1024
#define ACT 32
#define DETER 4096
#define TOKEN_DIM 512
#define HIDDEN 1024
#define NHEADS 8
#define HEADDIM 128
#define DSTATE 64
#define CONV_DIM 1152
#define IN_PROJ_DIM 2184
#define IPP 2240          // in_proj padded to 35*64
#define KIN 1088          // input GEMM K padded to 17*64
#define EPS 0.0001f

typedef float f32x4 __attribute__((ext_vector_type(4)));
typedef __bf16 bf16x8 __attribute__((ext_vector_type(8)));
typedef __bf16 bf16x4 __attribute__((ext_vector_type(4)));

// ---------------- fused weight conversion/padding (f32 -> bf16) ----------------
// w0: [512][1088]  (in_proj_w [512][1056], zero pad cols)
// w1: [2][2240][512] (blk_in_w [2][2184][512], zero pad rows)
// w2: [2][512][1024] (blk_out_w straight)
#define N0C (512 * KIN / 4)
#define N1C (2 * IPP * TOKEN_DIM / 4)
#define N2C (2 * TOKEN_DIM * HIDDEN / 4)
__global__ __launch_bounds__(256) void prep_weights(
    const float* __restrict__ inproj, const float* __restrict__ blkin,
    const float* __restrict__ blkout,
    __bf16* __restrict__ w0, __bf16* __restrict__ w1, __bf16* __restrict__ w2)
{
    int i = blockIdx.x * 256 + threadIdx.x;
    bf16x4 o = { (__bf16)0.f, (__bf16)0.f, (__bf16)0.f, (__bf16)0.f };
    if (i < N0C) {
        int idx = i * 4;
        int rr = idx / KIN, cc = idx % KIN;
        if (cc < STOCH + ACT) {
            float4 v = *(const float4*)(inproj + (size_t)rr * (STOCH + ACT) + cc);
            o = bf16x4{ (__bf16)v.x, (__bf16)v.y, (__bf16)v.z, (__bf16)v.w };
        }
        ((bf16x4*)w0)[i] = o;
    } else if (i < N0C + N1C) {
        int j = i - N0C;
        int idx = j * 4;
        int li  = idx / (IPP * TOKEN_DIM);
        int rem = idx % (IPP * TOKEN_DIM);
        int rr  = rem / TOKEN_DIM, cc = rem % TOKEN_DIM;
        if (rr < IN_PROJ_DIM) {
            float4 v = *(const float4*)(blkin + ((size_t)li * IN_PROJ_DIM + rr) * TOKEN_DIM + cc);
            o = bf16x4{ (__bf16)v.x, (__bf16)v.y, (__bf16)v.z, (__bf16)v.w };
        }
        ((bf16x4*)w1)[j] = o;
    } else if (i < N0C + N1C + N2C) {
        int j = i - N0C - N1C;
        float4 v = ((const float4*)blkout)[j];
        o = bf16x4{ (__bf16)v.x, (__bf16)v.y, (__bf16)v.z, (__bf16)v.w };
        ((bf16x4*)w2)[j] = o;
    }
}

// ---------------- MFMA GEMM, 64x64 tile, BK=64, XOR-swizzled LDS ----------------
// C(f32, MxN) = A_bf16(MxK) @ W_bf16(NxK)^T  (+bias) (+add)
// Requires M%64==0, N%64==0, K%64==0.
__global__ __launch_bounds__(256) void gemm_bf16_sw(
    const __bf16* __restrict__ A,
    const __bf16* __restrict__ W,
    const float* __restrict__ bias,
    const float* __restrict__ add,
    float* __restrict__ C,
    int M, int N, int K)
{
    __shared__ __bf16 As[64 * 64];   // 64 rows x 128B, XOR-swizzled
    __shared__ __bf16 Ws[64 * 64];
    const int tid = threadIdx.x;
    const int bm = blockIdx.y * 64;
    const int bn = blockIdx.x * 64;
    const int wid = tid >> 6;
    const int lane = tid & 63;
    const int wr = (wid >> 1) * 32;
    const int wc = (wid & 1) * 32;
    const int r = lane & 15;
    const int g16 = (lane >> 4) * 16;   // byte col of frag base within 64B half

    // staging: thread loads 16B from global (linear), writes swizzled LDS
    const int row0 = tid >> 3;               // 0..31
    const int colb = (tid * 16) & 0x70;      // byte col in 128B row
    const int wof0 = row0 * 128 + (colb ^ ((row0 & 7) << 4));
    const int wof1 = wof0 + 32 * 128;        // (row0+32)&7 == row0&7

    const __bf16* ga0 = A + (size_t)(bm + row0) * K + (colb >> 1);
    const __bf16* ga1 = ga0 + (size_t)32 * K;
    const __bf16* gw0 = W + (size_t)(bn + row0) * K + (colb >> 1);
    const __bf16* gw1 = gw0 + (size_t)32 * K;

    const int arow = wr + r;
    const int brow = wc + r;
    const int aswz = (arow & 7) << 4;
    const int bswz = (brow & 7) << 4;
    char* Asb = (char*)As;
    char* Wsb = (char*)Ws;

    f32x4 acc[2][2] = {};
    bf16x8 va0 = *(const bf16x8*)ga0;
    bf16x8 va1 = *(const bf16x8*)ga1;
    bf16x8 vw0 = *(const bf16x8*)gw0;
    bf16x8 vw1 = *(const bf16x8*)gw1;

    const int nsteps = K >> 6;
    for (int s = 0; s < nsteps; ++s) {
        __syncthreads();   // LDS free (prev compute done)
        *(bf16x8*)(Asb + wof0) = va0;
        *(bf16x8*)(Asb + wof1) = va1;
        *(bf16x8*)(Wsb + wof0) = vw0;
        *(bf16x8*)(Wsb + wof1) = vw1;
        __syncthreads();
        if (s + 1 < nsteps) {       // prefetch next tile; overlaps MFMA below
            const int ko = (s + 1) << 6;
            va0 = *(const bf16x8*)(ga0 + ko);
            va1 = *(const bf16x8*)(ga1 + ko);
            vw0 = *(const bf16x8*)(gw0 + ko);
            vw1 = *(const bf16x8*)(gw1 + ko);
        }
        #pragma unroll
        for (int ks = 0; ks < 2; ++ks) {
            const int cb = ks * 64 + g16;
            bf16x8 a0 = *(const bf16x8*)(Asb + arow * 128 + (cb ^ aswz));
            bf16x8 a1 = *(const bf16x8*)(Asb + (arow + 16) * 128 + (cb ^ aswz));
            bf16x8 b0 = *(const bf16x8*)(Wsb + brow * 128 + (cb ^ bswz));
            bf16x8 b1 = *(const bf16x8*)(Wsb + (brow + 16) * 128 + (cb ^ bswz));
            acc[0][0] = __builtin_amdgcn_mfma_f32_16x16x32_bf16(a0, b0, acc[0][0], 0, 0, 0);
            acc[0][1] = __builtin_amdgcn_mfma_f32_16x16x32_bf16(a0, b1, acc[0][1], 0, 0, 0);
            acc[1][0] = __builtin_amdgcn_mfma_f32_16x16x32_bf16(a1, b0, acc[1][0], 0, 0, 0);
            acc[1][1] = __builtin_amdgcn_mfma_f32_16x16x32_bf16(a1, b1, acc[1][1], 0, 0, 0);
        }
    }

    const int cr = (lane >> 4) * 4;
    const int cc = lane & 15;
    #pragma unroll
    for (int mi = 0; mi < 2; mi++) {
        #pragma unroll
        for (int ni = 0; ni < 2; ni++) {
            int n = bn + wc + ni * 16 + cc;
            #pragma unroll
            for (int j = 0; j < 4; j++) {
                int m = bm + wr + mi * 16 + cr + j;
                float v = acc[mi][ni][j];
                if (bias) v += bias[n];
                if (add)  v += add[(size_t)m * N + n];
                C[(size_t)m * N + n] = v;
            }
        }
    }
}

// ---------------- rmsnorm (one block per row) ----------------
template<int D, bool SILU, typename OutT>
__global__ __launch_bounds__(256) void rmsnorm_kernel(
    const float* __restrict__ x, const float* __restrict__ w, OutT* __restrict__ out)
{
    constexpr int VPT = D / 256;
    int b = blockIdx.x;
    const float* row = x + (size_t)b * D;
    float v[VPT];
    float ss = 0.f;
    #pragma unroll
    for (int i = 0; i < VPT; i++) {
        v[i] = row[threadIdx.x + i * 256];
        ss += v[i] * v[i];
    }
    #pragma unroll
    for (int off = 32; off >= 1; off >>= 1) ss += __shfl_xor(ss, off);
    __shared__ float red[4];
    if ((threadIdx.x & 63) == 0) red[threadIdx.x >> 6] = ss;
    __syncthreads();
    float tot = red[0] + red[1] + red[2] + red[3];
    float scale = rsqrtf(tot / (float)D + EPS);
    OutT* orow = out + (size_t)b * D;
    #pragma unroll
    for (int i = 0; i < VPT; i++) {
        float val = v[i] * scale * w[threadIdx.x + i * 256];
        if (SILU) val = val / (1.f + expf(-val));
        orow[threadIdx.x + i * 256] = (OutT)val;
    }
}

// gated = rmsnorm(y * silu(z), pw) -> bf16 ; z = proj[:, :HIDDEN] (stride IPP)
__global__ __launch_bounds__(256) void gate_rmsnorm_kernel(
    const float* __restrict__ y, const float* __restrict__ proj,
    const float* __restrict__ pw, __bf16* __restrict__ out)
{
    int b = blockIdx.x;
    const float* yr = y + (size_t)b * HIDDEN;
    const float* zr = proj + (size_t)b * IPP;
    float v[4];
    float ss = 0.f;
    #pragma unroll
    for (int i = 0; i < 4; i++) {
        int j = threadIdx.x + i * 256;
        float z = zr[j];
        float val = yr[j] * (z / (1.f + expf(-z)));
        v[i] = val;
        ss += val * val;
    }
    #pragma unroll
    for (int off = 32; off >= 1; off >>= 1) ss += __shfl_xor(ss, off);
    __shared__ float red[4];
    if ((threadIdx.x & 63) == 0) red[threadIdx.x >> 6] = ss;
    __syncthreads();
    float tot = red[0] + red[1] + red[2] + red[3];
    float scale = rsqrtf(tot / (float)HIDDEN + EPS);
    __bf16* orow = out + (size_t)b * HIDDEN;
    #pragma unroll
    for (int i = 0; i < 4; i++) {
        int j = threadIdx.x + i * 256;
        orow[j] = (__bf16)(v[i] * scale * pw[j]);
    }
}

// ---------------- prep input: [stoch | action/max(|a|,1) | 0 pad] -> bf16 ----------------
__global__ __launch_bounds__(256) void prep_inp_kernel(
    const float* __restrict__ stoch, const float* __restrict__ action, __bf16* __restrict__ inp)
{
    int idx = blockIdx.x * 256 + threadIdx.x;
    if (idx >= B_SZ * KIN) return;
    int b = idx / KIN;
    int j = idx - b * KIN;
    float v = 0.f;
    if (j < STOCH) {
        v = stoch[(size_t)b * STOCH + j];
    } else if (j < STOCH + ACT) {
        float a = action[(size_t)b * ACT + (j - STOCH)];
        float m = fabsf(a);
        v = a / (m > 1.f ? m : 1.f);
    }
    inp[idx] = (__bf16)v;
}

// ---------------- conv step (proj stride IPP) ----------------
__global__ __launch_bounds__(256) void conv_kernel(
    const float* __restrict__ cs,      // B x CONV_DIM x 3
    const float* __restrict__ proj,    // B x IPP
    const float* __restrict__ cw,      // CONV_DIM x 4
    const float* __restrict__ cb,      // CONV_DIM
    float* __restrict__ convout,       // B x CONV_DIM
    float* __restrict__ new_cs)        // B x CONV_DIM x 3
{
    int idx = blockIdx.x * 256 + threadIdx.x;
    if (idx >= B_SZ * CONV_DIM) return;
    int b = idx / CONV_DIM;
    int c = idx - b * CONV_DIM;
    const float* s = cs + ((size_t)b * CONV_DIM + c) * 3;
    float s0 = s[0], s1 = s[1], s2 = s[2];
    float xbc = proj[(size_t)b * IPP + HIDDEN + c];
    const float* wv = cw + c * 4;
    float v = wv[0] * s0 + wv[1] * s1 + wv[2] * s2 + wv[3] * xbc + cb[c];
    v = v / (1.f + expf(-v));
    convout[idx] = v;
    float* nc = new_cs + ((size_t)b * CONV_DIM + c) * 3;
    nc[0] = s1; nc[1] = s2; nc[2] = xbc;
}

// ---------------- SSM state update (coalesced) ----------------
__global__ __launch_bounds__(256) void ssm_kernel(
    const float* __restrict__ ss,    // B x NHEADS x HEADDIM x DSTATE
    const float* __restrict__ conv,  // B x CONV_DIM
    const float* __restrict__ proj,  // B x IPP
    const float* __restrict__ dtb,   // NHEADS
    const float* __restrict__ alog,  // NHEADS
    const float* __restrict__ Dv,    // NHEADS
    float* __restrict__ new_ss,      // out
    float* __restrict__ y)           // B x HIDDEN
{
    int b = blockIdx.x >> 3;
    int h = blockIdx.x & 7;
    int t = threadIdx.x;

    float dtr = proj[(size_t)b * IPP + HIDDEN + CONV_DIM + h] + dtb[h];
    float dt = dtr > 20.f ? dtr : log1pf(expf(dtr));
    float dA = expf(dt * -expf(alog[h]));
    float Dk = Dv[h];

    __shared__ float Bs[DSTATE], Cs[DSTATE];
    if (t < DSTATE) Bs[t] = conv[(size_t)b * CONV_DIM + HIDDEN + t];
    else if (t < 2 * DSTATE) Cs[t - DSTATE] = conv[(size_t)b * CONV_DIM + HIDDEN + DSTATE + (t - DSTATE)];
    __syncthreads();

    const int p0 = t >> 4;            // 0..15
    const int nq = (t & 15) * 4;      // 0..60
    float4 Bv = *(const float4*)&Bs[nq];
    float4 Cv = *(const float4*)&Cs[nq];

    const float* basep = ss + ((size_t)b * NHEADS + h) * HEADDIM * DSTATE;
    float* baseo = new_ss + ((size_t)b * NHEADS + h) * HEADDIM * DSTATE;
    const float* xrow = conv + (size_t)b * CONV_DIM + h * HEADDIM;
    float* yrow = y + (size_t)b * HIDDEN + h * HEADDIM;

    #pragma unroll
    for (int it = 0; it < 8; ++it) {
        int p = it * 16 + p0;
        float xp = xrow[p];
        float dtx = dt * xp;
        float4 s4 = *(const float4*)(basep + (size_t)p * DSTATE + nq);
        float4 o;
        o.x = fmaf(s4.x, dA, dtx * Bv.x);
        o.y = fmaf(s4.y, dA, dtx * Bv.y);
        o.z = fmaf(s4.z, dA, dtx * Bv.z);
        o.w = fmaf(s4.w, dA, dtx * Bv.w);
        *(float4*)(baseo + (size_t)p * DSTATE + nq) = o;
        float acc = o.x * Cv.x + o.y * Cv.y + o.z * Cv.z + o.w * Cv.w;
        acc += __shfl_xor(acc, 1);
        acc += __shfl_xor(acc, 2);
        acc += __shfl_xor(acc, 4);
        acc += __shfl_xor(acc, 8);
        if ((t & 15) == 0) yrow[p] = acc + Dk * xp;
    }
}

// ---------------- final: rmsnorm(X) fused with tape shift ----------------
__global__ __launch_bounds__(256) void final_kernel(
    const float* __restrict__ X, const float* __restrict__ w,
    const float* __restrict__ deter, float* __restrict__ out)
{
    int b = blockIdx.x;
    int t = threadIdx.x;
    float v0 = X[(size_t)b * TOKEN_DIM + t];
    float v1 = X[(size_t)b * TOKEN_DIM + 256 + t];
    float ss = v0 * v0 + v1 * v1;
    #pragma unroll
    for (int off = 32; off >= 1; off >>= 1) ss += __shfl_xor(ss, off);
    __shared__ float red[4];
    if ((t & 63) == 0) red[t >> 6] = ss;
    __syncthreads();
    float tot = red[0] + red[1] + red[2] + red[3];
    float scale = rsqrtf(tot / (float)TOKEN_DIM + EPS);
    out[(size_t)b * DETER + 3584 + t] = v0 * scale * w[t];
    out[(size_t)b * DETER + 3584 + 256 + t] = v1 * scale * w[256 + t];
    const float4* src = (const float4*)(deter + (size_t)b * DETER + TOKEN_DIM);
    float4* dst = (float4*)(out + (size_t)b * DETER);
    #pragma unroll
    for (int j = 0; j < 4; ++j) {
        int idx = t + j * 256;
        if (idx < 896) dst[idx] = src[idx];
    }
}

// ---------------- launch ----------------
extern "C" void kernel_launch(void* const* d_in, const int* in_sizes, int n_in,
                              void* d_out, int out_size, void* d_ws, size_t ws_size,
                              hipStream_t stream) {
    const float* stoch      = (const float*)d_in[0];
    const float* deter      = (const float*)d_in[1];
    const float* action     = (const float*)d_in[2];
    const float* conv_state = (const float*)d_in[3];
    const float* ssm_state  = (const float*)d_in[4];
    const float* in_proj_w  = (const float*)d_in[5];
    const float* in_proj_b  = (const float*)d_in[6];
    const float* in_norm_w  = (const float*)d_in[7];
    const float* blk_norm_w = (const float*)d_in[8];
    const float* blk_in_w   = (const float*)d_in[9];
    const float* blk_conv_w = (const float*)d_in[10];
    const float* blk_conv_b = (const float*)d_in[11];
    const float* blk_A_log  = (const float*)d_in[12];
    const float* blk_D      = (const float*)d_in[13];
    const float* blk_dt_bias= (const float*)d_in[14];
    const float* blk_post_norm_w = (const float*)d_in[15];
    const float* blk_out_w  = (const float*)d_in[16];
    const float* blk_out_b  = (const float*)d_in[17];
    const float* out_norm_w = (const float*)d_in[18];

    float* out_deter = (float*)d_out;
    float* out_cs    = out_deter + (size_t)B_SZ * DETER;
    float* out_ss    = out_cs + (size_t)2 * B_SZ * CONV_DIM * 3;

    char* ws = (char*)d_ws;
    __bf16* Wb_inproj = (__bf16*)ws;  ws += (size_t)TOKEN_DIM * KIN * 2;
    __bf16* Wb_blkin  = (__bf16*)ws;  ws += (size_t)2 * IPP * TOKEN_DIM * 2;
    __bf16* Wb_blkout = (__bf16*)ws;  ws += (size_t)2 * TOKEN_DIM * HIDDEN * 2;
    float*  X         = (float*)ws;   ws += (size_t)B_SZ * TOKEN_DIM * 4;
    __bf16* Hb        = (__bf16*)ws;  ws += (size_t)B_SZ * TOKEN_DIM * 2;
    float*  PROJ      = (float*)ws;   ws += (size_t)B_SZ * IPP * 4;
    float*  CONV      = (float*)ws;   ws += (size_t)B_SZ * CONV_DIM * 4;
    float*  Y         = (float*)ws;   ws += (size_t)B_SZ * HIDDEN * 4;
    __bf16* Gb        = (__bf16*)ws;  ws += (size_t)B_SZ * HIDDEN * 2;
    __bf16* INPb = (__bf16*)Y;   // alias: INP consumed before layer-0 ssm writes Y

    // 0. weights -> bf16 (padded)
    {
        int total = N0C + N1C + N2C;
        prep_weights<<<(total + 255) / 256, 256, 0, stream>>>(
            in_proj_w, blk_in_w, blk_out_w, Wb_inproj, Wb_blkin, Wb_blkout);
    }
    // 1. inp (bf16, padded K)
    {
        int n = B_SZ * KIN;
        prep_inp_kernel<<<(n + 255) / 256, 256, 0, stream>>>(stoch, action, INPb);
    }
    // 2. H512 = inp @ in_proj_w.T + b (into PROJ, stride 512); X = silu(rmsnorm(.))
    {
        dim3 grid(TOKEN_DIM / 64, B_SZ / 64);
        gemm_bf16_sw<<<grid, 256, 0, stream>>>(INPb, Wb_inproj, in_proj_b, nullptr, PROJ,
                                               B_SZ, TOKEN_DIM, KIN);
        rmsnorm_kernel<TOKEN_DIM, true, float><<<B_SZ, 256, 0, stream>>>(PROJ, in_norm_w, X);
    }

    for (int l = 0; l < 2; ++l) {
        const float* nw  = blk_norm_w + (size_t)l * TOKEN_DIM;
        const __bf16* iw = Wb_blkin + (size_t)l * IPP * TOKEN_DIM;
        const float* cw  = blk_conv_w + (size_t)l * CONV_DIM * 4;
        const float* cb  = blk_conv_b + (size_t)l * CONV_DIM;
        const float* alog= blk_A_log + (size_t)l * NHEADS;
        const float* Dv  = blk_D + (size_t)l * NHEADS;
        const float* dtb = blk_dt_bias + (size_t)l * NHEADS;
        const float* pw  = blk_post_norm_w + (size_t)l * HIDDEN;
        const __bf16* ow = Wb_blkout + (size_t)l * TOKEN_DIM * HIDDEN;
        const float* ob  = blk_out_b + (size_t)l * TOKEN_DIM;
        const float* cs_in = conv_state + (size_t)l * B_SZ * CONV_DIM * 3;
        const float* ss_in = ssm_state + (size_t)l * B_SZ * NHEADS * HEADDIM * DSTATE;
        float* cs_out = out_cs + (size_t)l * B_SZ * CONV_DIM * 3;
        float* ss_out = out_ss + (size_t)l * B_SZ * NHEADS * HEADDIM * DSTATE;

        rmsnorm_kernel<TOKEN_DIM, false, __bf16><<<B_SZ, 256, 0, stream>>>(X, nw, Hb);
        {
            dim3 grid(IPP / 64, B_SZ / 64);
            gemm_bf16_sw<<<grid, 256, 0, stream>>>(Hb, iw, nullptr, nullptr, PROJ,
                                                   B_SZ, IPP, TOKEN_DIM);
        }
        {
            int n = B_SZ * CONV_DIM;
            conv_kernel<<<(n + 255) / 256, 256, 0, stream>>>(cs_in, PROJ, cw, cb, CONV, cs_out);
        }
        ssm_kernel<<<B_SZ * NHEADS, 256, 0, stream>>>(ss_in, CONV, PROJ, dtb, alog, Dv, ss_out, Y);
        gate_rmsnorm_kernel<<<B_SZ, 256, 0, stream>>>(Y, PROJ, pw, Gb);
        {
            dim3 grid(TOKEN_DIM / 64, B_SZ / 64);
            gemm_bf16_sw<<<grid, 256, 0, stream>>>(Gb, ow, ob, X, X,
                                                   B_SZ, TOKEN_DIM, HIDDEN);
        }
    }

    final_kernel<<<B_SZ, 256, 0, stream>>>(X, out_norm_w, deter, out_deter);
}

// Round 4
// 308.438 us; speedup vs baseline: 2.4730x; 1.0724x over previous
//
#include <hip/hip_runtime.h>
#include <hip/hip_bf16.h>
#include <math.h>

#define B_SZ 1024
#define STOCH 1024
#define ACT 32
#define DETER 4096
#define TOKEN_DIM 512
#define HIDDEN 1024
#define NHEADS 8
#define HEADDIM 128
#define DSTATE 64
#define CONV_DIM 1152
#define IN_PROJ_DIM 2184
#define IPP2 2304         // in_proj N padded to 36*64
#define KIN 1088          // input GEMM K padded to 17*64
#define EPS 0.0001f

typedef float f32x4 __attribute__((ext_vector_type(4)));
typedef __bf16 bf16x8 __attribute__((ext_vector_type(8)));
typedef __bf16 bf16x4 __attribute__((ext_vector_type(4)));

// ---------------- fused weight conversion/padding (f32 -> bf16) ----------------
// w0: [512][1088]   (in_proj_w [512][1056], zero-pad cols)
// w1: [2][2304][512] (blk_in_w [2][2184][512], zero-pad rows)
// w2: [2][512][1024] (blk_out_w straight)
#define N0C (512 * KIN / 4)
#define N1C (2 * IPP2 * TOKEN_DIM / 4)
#define N2C (2 * TOKEN_DIM * HIDDEN / 4)
__global__ __launch_bounds__(256) void prep_weights(
    const float* __restrict__ inproj, const float* __restrict__ blkin,
    const float* __restrict__ blkout,
    __bf16* __restrict__ w0, __bf16* __restrict__ w1, __bf16* __restrict__ w2)
{
    int i = blockIdx.x * 256 + threadIdx.x;
    bf16x4 o = { (__bf16)0.f, (__bf16)0.f, (__bf16)0.f, (__bf16)0.f };
    if (i < N0C) {
        int idx = i * 4;
        int rr = idx / KIN, cc = idx % KIN;
        if (cc < STOCH + ACT) {
            float4 v = *(const float4*)(inproj + (size_t)rr * (STOCH + ACT) + cc);
            o = bf16x4{ (__bf16)v.x, (__bf16)v.y, (__bf16)v.z, (__bf16)v.w };
        }
        ((bf16x4*)w0)[i] = o;
    } else if (i < N0C + N1C) {
        int j = i - N0C;
        int idx = j * 4;
        int li  = idx / (IPP2 * TOKEN_DIM);
        int rem = idx % (IPP2 * TOKEN_DIM);
        int rr  = rem / TOKEN_DIM, cc = rem % TOKEN_DIM;
        if (rr < IN_PROJ_DIM) {
            float4 v = *(const float4*)(blkin + ((size_t)li * IN_PROJ_DIM + rr) * TOKEN_DIM + cc);
            o = bf16x4{ (__bf16)v.x, (__bf16)v.y, (__bf16)v.z, (__bf16)v.w };
        }
        ((bf16x4*)w1)[j] = o;
    } else if (i < N0C + N1C + N2C) {
        int j = i - N0C - N1C;
        float4 v = ((const float4*)blkout)[j];
        o = bf16x4{ (__bf16)v.x, (__bf16)v.y, (__bf16)v.z, (__bf16)v.w };
        ((bf16x4*)w2)[j] = o;
    }
}

// ---------------- prep input: [stoch | action/max(|a|,1) | 0 pad] -> bf16 ----------------
__global__ __launch_bounds__(256) void prep_inp_kernel(
    const float* __restrict__ stoch, const float* __restrict__ action, __bf16* __restrict__ inp)
{
    int idx = blockIdx.x * 256 + threadIdx.x;
    if (idx >= B_SZ * KIN) return;
    int b = idx / KIN;
    int j = idx - b * KIN;
    float v = 0.f;
    if (j < STOCH) {
        v = stoch[(size_t)b * STOCH + j];
    } else if (j < STOCH + ACT) {
        float a = action[(size_t)b * ACT + (j - STOCH)];
        float m = fabsf(a);
        v = a / (m > 1.f ? m : 1.f);
    }
    inp[idx] = (__bf16)v;
}

// ---------------- GEMM v2: 128x64 wg tile, wave 32x64, optional split-K ----------
// C(f32) = A_bf16(MxK) @ W_bf16(NxK)^T   M%128==0, N%64==0, K%64==0
// SPLIT: blockIdx.z = chunk, each handles `chunk_steps` K-steps of 64, raw partial out.
template<bool SPLIT>
__global__ __launch_bounds__(256) void gemm_v2(
    const __bf16* __restrict__ A,
    const __bf16* __restrict__ W,
    const float* __restrict__ bias,   // only used when !SPLIT (may be null)
    float* __restrict__ C,            // !SPLIT: MxN ; SPLIT: [z][M][N]
    int M, int N, int K, int chunk_steps)
{
    __shared__ __bf16 As[128 * 64];   // 128 rows x 128B, XOR-swizzled
    __shared__ __bf16 Ws[64 * 64];
    const int tid = threadIdx.x;
    const int bn = blockIdx.x * 64;
    const int bm = blockIdx.y * 128;
    const int nsteps = K >> 6;
    int s_begin = 0, s_end = nsteps;
    float* Cout = C;
    if (SPLIT) {
        int z = blockIdx.z;
        s_begin = z * chunk_steps;
        int se = s_begin + chunk_steps;
        s_end = se < nsteps ? se : nsteps;
        Cout = C + (size_t)z * M * N;
    }

    const int wid = tid >> 6;
    const int lane = tid & 63;
    const int wr = wid * 32;          // wave rows within 128
    const int r = lane & 15;
    const int kb = (lane >> 4) * 16;  // byte offset of k-group in 64B half

    // staging: 6 x 16B per thread per step
    const int row0 = tid >> 3;               // 0..31
    const int colb = (tid & 7) * 16;         // byte col in 128B row
    const int wof = row0 * 128 + (colb ^ ((row0 & 7) << 4));  // (row+32k)&7 invariant
    char* Asb = (char*)As;
    char* Wsb = (char*)Ws;

    const __bf16* gA = A + (size_t)(bm + row0) * K + (s_begin << 6) + (colb >> 1);
    const __bf16* gW = W + (size_t)(bn + row0) * K + (s_begin << 6) + (colb >> 1);
    const size_t aK32 = (size_t)32 * K;

    const int ar0 = wr + r;
    const int ar1 = wr + 16 + r;
    const int aswz = (ar0 & 7) << 4;
    const int bswz = (r & 7) << 4;

    f32x4 acc[2][4] = {};
    bf16x8 va0 = *(const bf16x8*)(gA);
    bf16x8 va1 = *(const bf16x8*)(gA + aK32);
    bf16x8 va2 = *(const bf16x8*)(gA + 2 * aK32);
    bf16x8 va3 = *(const bf16x8*)(gA + 3 * aK32);
    bf16x8 vw0 = *(const bf16x8*)(gW);
    bf16x8 vw1 = *(const bf16x8*)(gW + aK32);

    for (int s = s_begin; s < s_end; ++s) {
        __syncthreads();
        *(bf16x8*)(Asb + wof) = va0;
        *(bf16x8*)(Asb + wof + 32 * 128) = va1;
        *(bf16x8*)(Asb + wof + 64 * 128) = va2;
        *(bf16x8*)(Asb + wof + 96 * 128) = va3;
        *(bf16x8*)(Wsb + wof) = vw0;
        *(bf16x8*)(Wsb + wof + 32 * 128) = vw1;
        __syncthreads();
        if (s + 1 < s_end) {
            const int ko = (s + 1 - s_begin) << 6;
            va0 = *(const bf16x8*)(gA + ko);
            va1 = *(const bf16x8*)(gA + aK32 + ko);
            va2 = *(const bf16x8*)(gA + 2 * aK32 + ko);
            va3 = *(const bf16x8*)(gA + 3 * aK32 + ko);
            vw0 = *(const bf16x8*)(gW + ko);
            vw1 = *(const bf16x8*)(gW + aK32 + ko);
        }
        #pragma unroll
        for (int ks = 0; ks < 2; ++ks) {
            const int cb = ks * 64 + kb;
            bf16x8 a0 = *(const bf16x8*)(Asb + ar0 * 128 + (cb ^ aswz));
            bf16x8 a1 = *(const bf16x8*)(Asb + ar1 * 128 + (cb ^ aswz));
            bf16x8 b0 = *(const bf16x8*)(Wsb + r * 128 + (cb ^ bswz));
            bf16x8 b1 = *(const bf16x8*)(Wsb + (r + 16) * 128 + (cb ^ bswz));
            bf16x8 b2 = *(const bf16x8*)(Wsb + (r + 32) * 128 + (cb ^ bswz));
            bf16x8 b3 = *(const bf16x8*)(Wsb + (r + 48) * 128 + (cb ^ bswz));
            acc[0][0] = __builtin_amdgcn_mfma_f32_16x16x32_bf16(a0, b0, acc[0][0], 0, 0, 0);
            acc[0][1] = __builtin_amdgcn_mfma_f32_16x16x32_bf16(a0, b1, acc[0][1], 0, 0, 0);
            acc[0][2] = __builtin_amdgcn_mfma_f32_16x16x32_bf16(a0, b2, acc[0][2], 0, 0, 0);
            acc[0][3] = __builtin_amdgcn_mfma_f32_16x16x32_bf16(a0, b3, acc[0][3], 0, 0, 0);
            acc[1][0] = __builtin_amdgcn_mfma_f32_16x16x32_bf16(a1, b0, acc[1][0], 0, 0, 0);
            acc[1][1] = __builtin_amdgcn_mfma_f32_16x16x32_bf16(a1, b1, acc[1][1], 0, 0, 0);
            acc[1][2] = __builtin_amdgcn_mfma_f32_16x16x32_bf16(a1, b2, acc[1][2], 0, 0, 0);
            acc[1][3] = __builtin_amdgcn_mfma_f32_16x16x32_bf16(a1, b3, acc[1][3], 0, 0, 0);
        }
    }

    const int cr = (lane >> 4) * 4;
    const int cc = lane & 15;
    #pragma unroll
    for (int mi = 0; mi < 2; mi++) {
        #pragma unroll
        for (int ni = 0; ni < 4; ni++) {
            int n = bn + ni * 16 + cc;
            #pragma unroll
            for (int j = 0; j < 4; j++) {
                int m = bm + wr + mi * 16 + cr + j;
                float v = acc[mi][ni][j];
                if (!SPLIT && bias) v += bias[n];
                Cout[(size_t)m * N + n] = v;
            }
        }
    }
}

// ---------------- block-wide sum helper (256 threads) ----------------
__device__ __forceinline__ float block_sum(float v, float* red, int t) {
    #pragma unroll
    for (int off = 32; off >= 1; off >>= 1) v += __shfl_xor(v, off);
    if ((t & 63) == 0) red[t >> 6] = v;
    __syncthreads();
    float tot = red[0] + red[1] + red[2] + red[3];
    __syncthreads();
    return tot;
}

// ---------------- reduce_in: X = silu(rmsnorm(ΣP+bias, inw)); Hb = bf16(rmsnorm(X, nw)) ----
__global__ __launch_bounds__(256) void reduce_in_kernel(
    const float* __restrict__ P,      // [4][B][512]
    const float* __restrict__ bias,
    const float* __restrict__ inw,
    const float* __restrict__ nw,
    float* __restrict__ X, __bf16* __restrict__ Hb)
{
    __shared__ float red[4];
    int b = blockIdx.x, t = threadIdx.x;
    const size_t stride = (size_t)B_SZ * TOKEN_DIM;
    float h[2];
    float ss = 0.f;
    #pragma unroll
    for (int i = 0; i < 2; i++) {
        int c = t + i * 256;
        size_t o = (size_t)b * TOKEN_DIM + c;
        float v = P[o] + P[o + stride] + P[o + 2 * stride] + P[o + 3 * stride] + bias[c];
        h[i] = v;
        ss += v * v;
    }
    float tot = block_sum(ss, red, t);
    float sc = rsqrtf(tot / (float)TOKEN_DIM + EPS);
    float ss2 = 0.f;
    #pragma unroll
    for (int i = 0; i < 2; i++) {
        int c = t + i * 256;
        float v = h[i] * sc * inw[c];
        v = v / (1.f + expf(-v));        // silu
        h[i] = v;
        X[(size_t)b * TOKEN_DIM + c] = v;
        ss2 += v * v;
    }
    float tot2 = block_sum(ss2, red, t);
    float sc2 = rsqrtf(tot2 / (float)TOKEN_DIM + EPS);
    #pragma unroll
    for (int i = 0; i < 2; i++) {
        int c = t + i * 256;
        Hb[(size_t)b * TOKEN_DIM + c] = (__bf16)(h[i] * sc2 * nw[c]);
    }
}

// ---------------- reduce_out: newX = X + ΣP + ob; MODE0: X,Hb=rms(newX,w); MODE1: final tape ----
template<int MODE>
__global__ __launch_bounds__(256) void reduce_out_kernel(
    const float* __restrict__ P,      // [4][B][512]
    const float* __restrict__ ob,
    const float* __restrict__ Xin,
    const float* __restrict__ w,      // MODE0: next blk_norm_w ; MODE1: out_norm_w
    float* __restrict__ X,            // MODE0 out
    __bf16* __restrict__ Hb,          // MODE0 out
    const float* __restrict__ deter,  // MODE1
    float* __restrict__ out)          // MODE1
{
    __shared__ float red[4];
    int b = blockIdx.x, t = threadIdx.x;
    const size_t stride = (size_t)B_SZ * TOKEN_DIM;
    float h[2];
    float ss = 0.f;
    #pragma unroll
    for (int i = 0; i < 2; i++) {
        int c = t + i * 256;
        size_t o = (size_t)b * TOKEN_DIM + c;
        float v = Xin[o] + P[o] + P[o + stride] + P[o + 2 * stride] + P[o + 3 * stride] + ob[c];
        h[i] = v;
        ss += v * v;
    }
    float tot = block_sum(ss, red, t);
    float sc = rsqrtf(tot / (float)TOKEN_DIM + EPS);
    if (MODE == 0) {
        #pragma unroll
        for (int i = 0; i < 2; i++) {
            int c = t + i * 256;
            size_t o = (size_t)b * TOKEN_DIM + c;
            X[o] = h[i];
            Hb[o] = (__bf16)(h[i] * sc * w[c]);
        }
    } else {
        #pragma unroll
        for (int i = 0; i < 2; i++) {
            int c = t + i * 256;
            out[(size_t)b * DETER + 3584 + c] = h[i] * sc * w[c];
        }
        const float4* src = (const float4*)(deter + (size_t)b * DETER + TOKEN_DIM);
        float4* dst = (float4*)(out + (size_t)b * DETER);
        #pragma unroll
        for (int j = 0; j < 4; ++j) {
            int idx = t + j * 256;
            if (idx < 896) dst[idx] = src[idx];
        }
    }
}

// ---------------- fused conv + ssm + gate-rmsnorm (one block per batch row) ----------------
__global__ __launch_bounds__(256) void conv_ssm_gate_kernel(
    const float* __restrict__ cs,      // B x CONV_DIM x 3
    const float* __restrict__ proj,    // B x IPP2
    const float* __restrict__ cw,      // CONV_DIM x 4
    const float* __restrict__ cb,      // CONV_DIM
    const float* __restrict__ dtb,     // NHEADS
    const float* __restrict__ alog,    // NHEADS
    const float* __restrict__ Dv,      // NHEADS
    const float* __restrict__ pw,      // HIDDEN
    const float* __restrict__ ss,      // B x NHEADS x HEADDIM x DSTATE
    float* __restrict__ new_cs,
    float* __restrict__ new_ss,
    __bf16* __restrict__ Gb)           // B x HIDDEN
{
    __shared__ float convs[CONV_DIM];  // x(1024) | B(64) | C(64)
    __shared__ float yrow[HIDDEN];
    __shared__ float dts[NHEADS], dAs[NHEADS], dvs[NHEADS];
    __shared__ float red[4];

    int b = blockIdx.x, t = threadIdx.x;

    if (t < NHEADS) {
        float dtr = proj[(size_t)b * IPP2 + HIDDEN + CONV_DIM + t] + dtb[t];
        float dt = dtr > 20.f ? dtr : log1pf(expf(dtr));
        dts[t] = dt;
        dAs[t] = expf(dt * -expf(alog[t]));
        dvs[t] = Dv[t];
    }
    // conv over 1152 channels
    for (int c = t; c < CONV_DIM; c += 256) {
        const float* s = cs + ((size_t)b * CONV_DIM + c) * 3;
        float s0 = s[0], s1 = s[1], s2 = s[2];
        float xbc = proj[(size_t)b * IPP2 + HIDDEN + c];
        float4 wv = *(const float4*)(cw + c * 4);
        float v = wv.x * s0 + wv.y * s1 + wv.z * s2 + wv.w * xbc + cb[c];
        v = v / (1.f + expf(-v));
        convs[c] = v;
        float* nc = new_cs + ((size_t)b * CONV_DIM + c) * 3;
        nc[0] = s1; nc[1] = s2; nc[2] = xbc;
    }
    __syncthreads();

    const int p0 = t >> 4;            // 0..15
    const int nq = (t & 15) * 4;      // 0..60
    float4 Bv = *(const float4*)&convs[HIDDEN + nq];
    float4 Cv = *(const float4*)&convs[HIDDEN + DSTATE + nq];
    const float* basep = ss + (size_t)b * NHEADS * HEADDIM * DSTATE;
    float* baseo = new_ss + (size_t)b * NHEADS * HEADDIM * DSTATE;

    for (int h = 0; h < NHEADS; ++h) {
        float dt = dts[h], dA = dAs[h], Dk = dvs[h];
        const float* sp = basep + (size_t)h * HEADDIM * DSTATE;
        float* op = baseo + (size_t)h * HEADDIM * DSTATE;
        #pragma unroll
        for (int it = 0; it < 8; ++it) {
            int p = it * 16 + p0;
            float xp = convs[h * HEADDIM + p];
            float dtx = dt * xp;
            float4 s4 = *(const float4*)(sp + (size_t)p * DSTATE + nq);
            float4 o;
            o.x = fmaf(s4.x, dA, dtx * Bv.x);
            o.y = fmaf(s4.y, dA, dtx * Bv.y);
            o.z = fmaf(s4.z, dA, dtx * Bv.z);
            o.w = fmaf(s4.w, dA, dtx * Bv.w);
            *(float4*)(op + (size_t)p * DSTATE + nq) = o;
            float acc = o.x * Cv.x + o.y * Cv.y + o.z * Cv.z + o.w * Cv.w;
            acc += __shfl_xor(acc, 1);
            acc += __shfl_xor(acc, 2);
            acc += __shfl_xor(acc, 4);
            acc += __shfl_xor(acc, 8);
            if ((t & 15) == 0) yrow[h * HEADDIM + p] = acc + Dk * xp;
        }
    }
    __syncthreads();

    // gate + rmsnorm over HIDDEN
    float vv[4];
    float ssum = 0.f;
    #pragma unroll
    for (int i = 0; i < 4; i++) {
        int j = t + i * 256;
        float z = proj[(size_t)b * IPP2 + j];
        float val = yrow[j] * (z / (1.f + expf(-z)));
        vv[i] = val;
        ssum += val * val;
    }
    float tot = block_sum(ssum, red, t);
    float sc = rsqrtf(tot / (float)HIDDEN + EPS);
    #pragma unroll
    for (int i = 0; i < 4; i++) {
        int j = t + i * 256;
        Gb[(size_t)b * HIDDEN + j] = (__bf16)(vv[i] * sc * pw[j]);
    }
}

// ---------------- launch ----------------
extern "C" void kernel_launch(void* const* d_in, const int* in_sizes, int n_in,
                              void* d_out, int out_size, void* d_ws, size_t ws_size,
                              hipStream_t stream) {
    const float* stoch      = (const float*)d_in[0];
    const float* deter      = (const float*)d_in[1];
    const float* action     = (const float*)d_in[2];
    const float* conv_state = (const float*)d_in[3];
    const float* ssm_state  = (const float*)d_in[4];
    const float* in_proj_w  = (const float*)d_in[5];
    const float* in_proj_b  = (const float*)d_in[6];
    const float* in_norm_w  = (const float*)d_in[7];
    const float* blk_norm_w = (const float*)d_in[8];
    const float* blk_in_w   = (const float*)d_in[9];
    const float* blk_conv_w = (const float*)d_in[10];
    const float* blk_conv_b = (const float*)d_in[11];
    const float* blk_A_log  = (const float*)d_in[12];
    const float* blk_D      = (const float*)d_in[13];
    const float* blk_dt_bias= (const float*)d_in[14];
    const float* blk_post_norm_w = (const float*)d_in[15];
    const float* blk_out_w  = (const float*)d_in[16];
    const float* blk_out_b  = (const float*)d_in[17];
    const float* out_norm_w = (const float*)d_in[18];

    float* out_deter = (float*)d_out;
    float* out_cs    = out_deter + (size_t)B_SZ * DETER;
    float* out_ss    = out_cs + (size_t)2 * B_SZ * CONV_DIM * 3;

    char* ws = (char*)d_ws;
    __bf16* Wb_inproj = (__bf16*)ws;  ws += (size_t)TOKEN_DIM * KIN * 2;
    __bf16* Wb_blkin  = (__bf16*)ws;  ws += (size_t)2 * IPP2 * TOKEN_DIM * 2;
    __bf16* Wb_blkout = (__bf16*)ws;  ws += (size_t)2 * TOKEN_DIM * HIDDEN * 2;
    float*  X         = (float*)ws;   ws += (size_t)B_SZ * TOKEN_DIM * 4;
    __bf16* Hb        = (__bf16*)ws;  ws += (size_t)B_SZ * TOKEN_DIM * 2;
    float*  PROJ      = (float*)ws;   ws += (size_t)B_SZ * IPP2 * 4;
    __bf16* Gb        = (__bf16*)ws;  ws += (size_t)B_SZ * HIDDEN * 2;
    float*  PART      = (float*)ws;   ws += (size_t)4 * B_SZ * TOKEN_DIM * 4;  // split-K partials
    __bf16* INPb = (__bf16*)PROJ;   // alias: consumed by gemm_input before PROJ written

    // 0. weights -> bf16 (padded)
    {
        int total = N0C + N1C + N2C;
        prep_weights<<<(total + 255) / 256, 256, 0, stream>>>(
            in_proj_w, blk_in_w, blk_out_w, Wb_inproj, Wb_blkin, Wb_blkout);
    }
    // 1. inp (bf16, padded K)
    {
        int n = B_SZ * KIN;
        prep_inp_kernel<<<(n + 255) / 256, 256, 0, stream>>>(stoch, action, INPb);
    }
    // 2. input GEMM (split-K 4: 17 steps -> 5,5,5,2) + fused reduce/rms/silu/rms
    {
        dim3 grid(TOKEN_DIM / 64, B_SZ / 128, 4);
        gemm_v2<true><<<grid, 256, 0, stream>>>(INPb, Wb_inproj, nullptr, PART,
                                                B_SZ, TOKEN_DIM, KIN, 5);
        reduce_in_kernel<<<B_SZ, 256, 0, stream>>>(PART, in_proj_b, in_norm_w,
                                                   blk_norm_w, X, Hb);
    }

    for (int l = 0; l < 2; ++l) {
        const __bf16* iw = Wb_blkin + (size_t)l * IPP2 * TOKEN_DIM;
        const float* cw  = blk_conv_w + (size_t)l * CONV_DIM * 4;
        const float* cbv = blk_conv_b + (size_t)l * CONV_DIM;
        const float* alog= blk_A_log + (size_t)l * NHEADS;
        const float* Dvv = blk_D + (size_t)l * NHEADS;
        const float* dtb = blk_dt_bias + (size_t)l * NHEADS;
        const float* pw  = blk_post_norm_w + (size_t)l * HIDDEN;
        const __bf16* ow = Wb_blkout + (size_t)l * TOKEN_DIM * HIDDEN;
        const float* ob  = blk_out_b + (size_t)l * TOKEN_DIM;
        const float* cs_in = conv_state + (size_t)l * B_SZ * CONV_DIM * 3;
        const float* ss_in = ssm_state + (size_t)l * B_SZ * NHEADS * HEADDIM * DSTATE;
        float* cs_out = out_cs + (size_t)l * B_SZ * CONV_DIM * 3;
        float* ss_out = out_ss + (size_t)l * B_SZ * NHEADS * HEADDIM * DSTATE;

        // in-proj GEMM (no split): N=2304
        {
            dim3 grid(IPP2 / 64, B_SZ / 128);
            gemm_v2<false><<<grid, 256, 0, stream>>>(Hb, iw, nullptr, PROJ,
                                                     B_SZ, IPP2, TOKEN_DIM, 0);
        }
        // fused conv + ssm + gate-rmsnorm
        conv_ssm_gate_kernel<<<B_SZ, 256, 0, stream>>>(
            cs_in, PROJ, cw, cbv, dtb, alog, Dvv, pw, ss_in, cs_out, ss_out, Gb);
        // out GEMM (split-K 4: 16 steps -> 4 each)
        {
            dim3 grid(TOKEN_DIM / 64, B_SZ / 128, 4);
            gemm_v2<true><<<grid, 256, 0, stream>>>(Gb, ow, nullptr, PART,
                                                    B_SZ, TOKEN_DIM, HIDDEN, 4);
        }
        // fused residual + rms (next layer or final tape)
        if (l == 0) {
            reduce_out_kernel<0><<<B_SZ, 256, 0, stream>>>(
                PART, ob, X, blk_norm_w + TOKEN_DIM, X, Hb, nullptr, nullptr);
        } else {
            reduce_out_kernel<1><<<B_SZ, 256, 0, stream>>>(
                PART, ob, X, out_norm_w, nullptr, nullptr, deter, out_deter);
        }
    }
}

// Round 5
// 300.039 us; speedup vs baseline: 2.5422x; 1.0280x over previous
//
#include <hip/hip_runtime.h>
#include <hip/hip_bf16.h>
#include <math.h>

#define B_SZ 1024
#define STOCH 1024
#define ACT 32
#define DETER 4096
#define TOKEN_DIM 512
#define HIDDEN 1024
#define NHEADS 8
#define HEADDIM 128
#define DSTATE 64
#define CONV_DIM 1152
#define IN_PROJ_DIM 2184
#define IPP2 2304         // in_proj N padded to 36*64
#define KIN 1088          // input GEMM K padded to 17*64
#define EPS 0.0001f

typedef float f32x4 __attribute__((ext_vector_type(4)));
typedef __bf16 bf16x8 __attribute__((ext_vector_type(8)));
typedef __bf16 bf16x4 __attribute__((ext_vector_type(4)));

// ---------------- fused prep: weights -> bf16 (padded) + input row build ----------------
#define N0C (512 * KIN / 4)
#define N1C (2 * IPP2 * TOKEN_DIM / 4)
#define N2C (2 * TOKEN_DIM * HIDDEN / 4)
#define N3C (B_SZ * KIN / 4)
__global__ __launch_bounds__(256) void prep_all(
    const float* __restrict__ inproj, const float* __restrict__ blkin,
    const float* __restrict__ blkout,
    const float* __restrict__ stoch, const float* __restrict__ action,
    __bf16* __restrict__ w0, __bf16* __restrict__ w1, __bf16* __restrict__ w2,
    __bf16* __restrict__ inp)
{
    int i = blockIdx.x * 256 + threadIdx.x;
    bf16x4 o = { (__bf16)0.f, (__bf16)0.f, (__bf16)0.f, (__bf16)0.f };
    if (i < N0C) {
        int idx = i * 4;
        int rr = idx / KIN, cc = idx % KIN;
        if (cc < STOCH + ACT) {
            float4 v = *(const float4*)(inproj + (size_t)rr * (STOCH + ACT) + cc);
            o = bf16x4{ (__bf16)v.x, (__bf16)v.y, (__bf16)v.z, (__bf16)v.w };
        }
        ((bf16x4*)w0)[i] = o;
    } else if (i < N0C + N1C) {
        int j = i - N0C;
        int idx = j * 4;
        int li  = idx / (IPP2 * TOKEN_DIM);
        int rem = idx % (IPP2 * TOKEN_DIM);
        int rr  = rem / TOKEN_DIM, cc = rem % TOKEN_DIM;
        if (rr < IN_PROJ_DIM) {
            float4 v = *(const float4*)(blkin + ((size_t)li * IN_PROJ_DIM + rr) * TOKEN_DIM + cc);
            o = bf16x4{ (__bf16)v.x, (__bf16)v.y, (__bf16)v.z, (__bf16)v.w };
        }
        ((bf16x4*)w1)[j] = o;
    } else if (i < N0C + N1C + N2C) {
        int j = i - N0C - N1C;
        float4 v = ((const float4*)blkout)[j];
        o = bf16x4{ (__bf16)v.x, (__bf16)v.y, (__bf16)v.z, (__bf16)v.w };
        ((bf16x4*)w2)[j] = o;
    } else if (i < N0C + N1C + N2C + N3C) {
        int j = i - N0C - N1C - N2C;
        int idx = j * 4;
        int b = idx / KIN, c = idx % KIN;
        if (c < STOCH) {
            float4 v = *(const float4*)(stoch + (size_t)b * STOCH + c);
            o = bf16x4{ (__bf16)v.x, (__bf16)v.y, (__bf16)v.z, (__bf16)v.w };
        } else if (c < STOCH + ACT) {
            float4 v = *(const float4*)(action + (size_t)b * ACT + (c - STOCH));
            float4 m;
            m.x = fabsf(v.x) > 1.f ? fabsf(v.x) : 1.f;
            m.y = fabsf(v.y) > 1.f ? fabsf(v.y) : 1.f;
            m.z = fabsf(v.z) > 1.f ? fabsf(v.z) : 1.f;
            m.w = fabsf(v.w) > 1.f ? fabsf(v.w) : 1.f;
            o = bf16x4{ (__bf16)(v.x / m.x), (__bf16)(v.y / m.y),
                        (__bf16)(v.z / m.z), (__bf16)(v.w / m.w) };
        }
        ((bf16x4*)inp)[j] = o;
    }
}

// ---------------- GEMM v2: 128x64 wg tile, wave 32x64, optional split-K ----------
// C = A_bf16(MxK) @ W_bf16(NxK)^T   M%128==0, N%64==0, K%64==0
template<bool SPLIT, typename OutT>
__global__ __launch_bounds__(256) void gemm_v2(
    const __bf16* __restrict__ A,
    const __bf16* __restrict__ W,
    const float* __restrict__ bias,   // only used when !SPLIT (may be null)
    OutT* __restrict__ C,             // !SPLIT: MxN ; SPLIT: [z][M][N]
    int M, int N, int K, int chunk_steps)
{
    __shared__ __bf16 As[128 * 64];   // 128 rows x 128B, XOR-swizzled
    __shared__ __bf16 Ws[64 * 64];
    const int tid = threadIdx.x;
    const int bn = blockIdx.x * 64;
    const int bm = blockIdx.y * 128;
    const int nsteps = K >> 6;
    int s_begin = 0, s_end = nsteps;
    OutT* Cout = C;
    if (SPLIT) {
        int z = blockIdx.z;
        s_begin = z * chunk_steps;
        int se = s_begin + chunk_steps;
        s_end = se < nsteps ? se : nsteps;
        Cout = C + (size_t)z * M * N;
    }

    const int wid = tid >> 6;
    const int lane = tid & 63;
    const int wr = wid * 32;
    const int r = lane & 15;
    const int kb = (lane >> 4) * 16;

    const int row0 = tid >> 3;
    const int colb = (tid & 7) * 16;
    const int wof = row0 * 128 + (colb ^ ((row0 & 7) << 4));
    char* Asb = (char*)As;
    char* Wsb = (char*)Ws;

    const __bf16* gA = A + (size_t)(bm + row0) * K + (s_begin << 6) + (colb >> 1);
    const __bf16* gW = W + (size_t)(bn + row0) * K + (s_begin << 6) + (colb >> 1);
    const size_t aK32 = (size_t)32 * K;

    const int ar0 = wr + r;
    const int ar1 = wr + 16 + r;
    const int aswz = (ar0 & 7) << 4;
    const int bswz = (r & 7) << 4;

    f32x4 acc[2][4] = {};
    bf16x8 va0 = *(const bf16x8*)(gA);
    bf16x8 va1 = *(const bf16x8*)(gA + aK32);
    bf16x8 va2 = *(const bf16x8*)(gA + 2 * aK32);
    bf16x8 va3 = *(const bf16x8*)(gA + 3 * aK32);
    bf16x8 vw0 = *(const bf16x8*)(gW);
    bf16x8 vw1 = *(const bf16x8*)(gW + aK32);

    for (int s = s_begin; s < s_end; ++s) {
        __syncthreads();
        *(bf16x8*)(Asb + wof) = va0;
        *(bf16x8*)(Asb + wof + 32 * 128) = va1;
        *(bf16x8*)(Asb + wof + 64 * 128) = va2;
        *(bf16x8*)(Asb + wof + 96 * 128) = va3;
        *(bf16x8*)(Wsb + wof) = vw0;
        *(bf16x8*)(Wsb + wof + 32 * 128) = vw1;
        __syncthreads();
        if (s + 1 < s_end) {
            const int ko = (s + 1 - s_begin) << 6;
            va0 = *(const bf16x8*)(gA + ko);
            va1 = *(const bf16x8*)(gA + aK32 + ko);
            va2 = *(const bf16x8*)(gA + 2 * aK32 + ko);
            va3 = *(const bf16x8*)(gA + 3 * aK32 + ko);
            vw0 = *(const bf16x8*)(gW + ko);
            vw1 = *(const bf16x8*)(gW + aK32 + ko);
        }
        #pragma unroll
        for (int ks = 0; ks < 2; ++ks) {
            const int cb = ks * 64 + kb;
            bf16x8 a0 = *(const bf16x8*)(Asb + ar0 * 128 + (cb ^ aswz));
            bf16x8 a1 = *(const bf16x8*)(Asb + ar1 * 128 + (cb ^ aswz));
            bf16x8 b0 = *(const bf16x8*)(Wsb + r * 128 + (cb ^ bswz));
            bf16x8 b1 = *(const bf16x8*)(Wsb + (r + 16) * 128 + (cb ^ bswz));
            bf16x8 b2 = *(const bf16x8*)(Wsb + (r + 32) * 128 + (cb ^ bswz));
            bf16x8 b3 = *(const bf16x8*)(Wsb + (r + 48) * 128 + (cb ^ bswz));
            acc[0][0] = __builtin_amdgcn_mfma_f32_16x16x32_bf16(a0, b0, acc[0][0], 0, 0, 0);
            acc[0][1] = __builtin_amdgcn_mfma_f32_16x16x32_bf16(a0, b1, acc[0][1], 0, 0, 0);
            acc[0][2] = __builtin_amdgcn_mfma_f32_16x16x32_bf16(a0, b2, acc[0][2], 0, 0, 0);
            acc[0][3] = __builtin_amdgcn_mfma_f32_16x16x32_bf16(a0, b3, acc[0][3], 0, 0, 0);
            acc[1][0] = __builtin_amdgcn_mfma_f32_16x16x32_bf16(a1, b0, acc[1][0], 0, 0, 0);
            acc[1][1] = __builtin_amdgcn_mfma_f32_16x16x32_bf16(a1, b1, acc[1][1], 0, 0, 0);
            acc[1][2] = __builtin_amdgcn_mfma_f32_16x16x32_bf16(a1, b2, acc[1][2], 0, 0, 0);
            acc[1][3] = __builtin_amdgcn_mfma_f32_16x16x32_bf16(a1, b3, acc[1][3], 0, 0, 0);
        }
    }

    const int cr = (lane >> 4) * 4;
    const int cc = lane & 15;
    #pragma unroll
    for (int mi = 0; mi < 2; mi++) {
        #pragma unroll
        for (int ni = 0; ni < 4; ni++) {
            int n = bn + ni * 16 + cc;
            #pragma unroll
            for (int j = 0; j < 4; j++) {
                int m = bm + wr + mi * 16 + cr + j;
                float v = acc[mi][ni][j];
                if (!SPLIT && bias) v += bias[n];
                Cout[(size_t)m * N + n] = (OutT)v;
            }
        }
    }
}

// ---------------- block-wide sum helper (256 threads) ----------------
__device__ __forceinline__ float block_sum(float v, float* red, int t) {
    #pragma unroll
    for (int off = 32; off >= 1; off >>= 1) v += __shfl_xor(v, off);
    if ((t & 63) == 0) red[t >> 6] = v;
    __syncthreads();
    float tot = red[0] + red[1] + red[2] + red[3];
    __syncthreads();
    return tot;
}

// ---------------- reduce_in: X = silu(rmsnorm(ΣP+bias, inw)); Hb = bf16(rmsnorm(X, nw)) ----
__global__ __launch_bounds__(256) void reduce_in_kernel(
    const float* __restrict__ P,      // [4][B][512]
    const float* __restrict__ bias,
    const float* __restrict__ inw,
    const float* __restrict__ nw,
    float* __restrict__ X, __bf16* __restrict__ Hb)
{
    __shared__ float red[4];
    int b = blockIdx.x, t = threadIdx.x;
    const size_t stride = (size_t)B_SZ * TOKEN_DIM;
    float h[2];
    float ss = 0.f;
    #pragma unroll
    for (int i = 0; i < 2; i++) {
        int c = t + i * 256;
        size_t o = (size_t)b * TOKEN_DIM + c;
        float v = P[o] + P[o + stride] + P[o + 2 * stride] + P[o + 3 * stride] + bias[c];
        h[i] = v;
        ss += v * v;
    }
    float tot = block_sum(ss, red, t);
    float sc = rsqrtf(tot / (float)TOKEN_DIM + EPS);
    float ss2 = 0.f;
    #pragma unroll
    for (int i = 0; i < 2; i++) {
        int c = t + i * 256;
        float v = h[i] * sc * inw[c];
        v = v / (1.f + expf(-v));        // silu
        h[i] = v;
        X[(size_t)b * TOKEN_DIM + c] = v;
        ss2 += v * v;
    }
    float tot2 = block_sum(ss2, red, t);
    float sc2 = rsqrtf(tot2 / (float)TOKEN_DIM + EPS);
    #pragma unroll
    for (int i = 0; i < 2; i++) {
        int c = t + i * 256;
        Hb[(size_t)b * TOKEN_DIM + c] = (__bf16)(h[i] * sc2 * nw[c]);
    }
}

// ---------------- reduce_out: newX = X + ΣP + ob; MODE0: X,Hb=rms(newX,w); MODE1: final tape ----
template<int MODE>
__global__ __launch_bounds__(256) void reduce_out_kernel(
    const float* __restrict__ P,      // [4][B][512]
    const float* __restrict__ ob,
    const float* __restrict__ Xin,
    const float* __restrict__ w,
    float* __restrict__ X,
    __bf16* __restrict__ Hb,
    const float* __restrict__ deter,
    float* __restrict__ out)
{
    __shared__ float red[4];
    int b = blockIdx.x, t = threadIdx.x;
    const size_t stride = (size_t)B_SZ * TOKEN_DIM;
    float h[2];
    float ss = 0.f;
    #pragma unroll
    for (int i = 0; i < 2; i++) {
        int c = t + i * 256;
        size_t o = (size_t)b * TOKEN_DIM + c;
        float v = Xin[o] + P[o] + P[o + stride] + P[o + 2 * stride] + P[o + 3 * stride] + ob[c];
        h[i] = v;
        ss += v * v;
    }
    float tot = block_sum(ss, red, t);
    float sc = rsqrtf(tot / (float)TOKEN_DIM + EPS);
    if (MODE == 0) {
        #pragma unroll
        for (int i = 0; i < 2; i++) {
            int c = t + i * 256;
            size_t o = (size_t)b * TOKEN_DIM + c;
            X[o] = h[i];
            Hb[o] = (__bf16)(h[i] * sc * w[c]);
        }
    } else {
        #pragma unroll
        for (int i = 0; i < 2; i++) {
            int c = t + i * 256;
            out[(size_t)b * DETER + 3584 + c] = h[i] * sc * w[c];
        }
        const float4* src = (const float4*)(deter + (size_t)b * DETER + TOKEN_DIM);
        float4* dst = (float4*)(out + (size_t)b * DETER);
        #pragma unroll
        for (int j = 0; j < 4; ++j) {
            int idx = t + j * 256;
            if (idx < 896) dst[idx] = src[idx];
        }
    }
}

// ---------------- fused conv + ssm + gate-rmsnorm (one block per batch row) ----------------
// v2: 64B/thread interleaved state access, f32x4 packed math, nontemporal stream,
//     2-shuffle C-dot reduce.
__global__ __launch_bounds__(256) void conv_ssm_gate_kernel(
    const float* __restrict__ cs,      // B x CONV_DIM x 3
    const __bf16* __restrict__ proj,   // B x IPP2 (bf16)
    const float* __restrict__ cw,      // CONV_DIM x 4
    const float* __restrict__ cb,      // CONV_DIM
    const float* __restrict__ dtb,     // NHEADS
    const float* __restrict__ alog,    // NHEADS
    const float* __restrict__ Dv,      // NHEADS
    const float* __restrict__ pw,      // HIDDEN
    const float* __restrict__ ss,      // B x NHEADS x HEADDIM x DSTATE
    float* __restrict__ new_cs,
    float* __restrict__ new_ss,
    __bf16* __restrict__ Gb)           // B x HIDDEN
{
    __shared__ float convs[CONV_DIM];  // x(1024) | B(64) | C(64)
    __shared__ float yrow[HIDDEN];
    __shared__ float dts[NHEADS], dAs[NHEADS], dvs[NHEADS];
    __shared__ float red[4];

    int b = blockIdx.x, t = threadIdx.x;
    const __bf16* prow = proj + (size_t)b * IPP2;

    if (t < NHEADS) {
        float dtr = (float)prow[HIDDEN + CONV_DIM + t] + dtb[t];
        float dt = dtr > 20.f ? dtr : log1pf(expf(dtr));
        dts[t] = dt;
        dAs[t] = expf(dt * -expf(alog[t]));
        dvs[t] = Dv[t];
    }
    // conv over 1152 channels
    for (int c = t; c < CONV_DIM; c += 256) {
        const float* s = cs + ((size_t)b * CONV_DIM + c) * 3;
        float s0 = s[0], s1 = s[1], s2 = s[2];
        float xbc = (float)prow[HIDDEN + c];
        float4 wv = *(const float4*)(cw + c * 4);
        float v = wv.x * s0 + wv.y * s1 + wv.z * s2 + wv.w * xbc + cb[c];
        v = v / (1.f + expf(-v));
        convs[c] = v;
        float* nc = new_cs + ((size_t)b * CONV_DIM + c) * 3;
        nc[0] = s1; nc[1] = s2; nc[2] = xbc;
    }
    __syncthreads();

    // SSM: thread owns quad q of p-row p0 (+64 per it); 4 interleaved f32x4 per (p, it)
    const int p0 = t >> 2;            // 0..63
    const int q  = t & 3;             // quad in row
    f32x4 Bv[4], Cv[4];
    #pragma unroll
    for (int j = 0; j < 4; ++j) {
        Bv[j] = *(const f32x4*)&convs[HIDDEN + q * 4 + j * 16];
        Cv[j] = *(const f32x4*)&convs[HIDDEN + DSTATE + q * 4 + j * 16];
    }
    const float* basep = ss + (size_t)b * NHEADS * HEADDIM * DSTATE;
    float* baseo = new_ss + (size_t)b * NHEADS * HEADDIM * DSTATE;

    for (int h = 0; h < NHEADS; ++h) {
        float dt = dts[h], dA = dAs[h], Dk = dvs[h];
        #pragma unroll
        for (int it = 0; it < 2; ++it) {
            int p = it * 64 + p0;
            float xp = convs[h * HEADDIM + p];
            float dtx = dt * xp;
            const float* sp = basep + ((size_t)h * HEADDIM + p) * DSTATE + q * 4;
            float* op = baseo + ((size_t)h * HEADDIM + p) * DSTATE + q * 4;
            f32x4 acc4 = {};
            #pragma unroll
            for (int j = 0; j < 4; ++j) {
                f32x4 s4 = __builtin_nontemporal_load((const f32x4*)(sp + j * 16));
                f32x4 o = s4 * dA + dtx * Bv[j];
                __builtin_nontemporal_store(o, (f32x4*)(op + j * 16));
                acc4 += o * Cv[j];
            }
            float acc = (acc4[0] + acc4[1]) + (acc4[2] + acc4[3]);
            acc += __shfl_xor(acc, 1);
            acc += __shfl_xor(acc, 2);
            if (q == 0) yrow[h * HEADDIM + p] = acc + Dk * xp;
        }
    }
    __syncthreads();

    // gate + rmsnorm over HIDDEN
    float vv[4];
    float ssum = 0.f;
    #pragma unroll
    for (int i = 0; i < 4; i++) {
        int j = t + i * 256;
        float z = (float)prow[j];
        float val = yrow[j] * (z / (1.f + expf(-z)));
        vv[i] = val;
        ssum += val * val;
    }
    float tot = block_sum(ssum, red, t);
    float sc = rsqrtf(tot / (float)HIDDEN + EPS);
    #pragma unroll
    for (int i = 0; i < 4; i++) {
        int j = t + i * 256;
        Gb[(size_t)b * HIDDEN + j] = (__bf16)(vv[i] * sc * pw[j]);
    }
}

// ---------------- launch ----------------
extern "C" void kernel_launch(void* const* d_in, const int* in_sizes, int n_in,
                              void* d_out, int out_size, void* d_ws, size_t ws_size,
                              hipStream_t stream) {
    const float* stoch      = (const float*)d_in[0];
    const float* deter      = (const float*)d_in[1];
    const float* action     = (const float*)d_in[2];
    const float* conv_state = (const float*)d_in[3];
    const float* ssm_state  = (const float*)d_in[4];
    const float* in_proj_w  = (const float*)d_in[5];
    const float* in_proj_b  = (const float*)d_in[6];
    const float* in_norm_w  = (const float*)d_in[7];
    const float* blk_norm_w = (const float*)d_in[8];
    const float* blk_in_w   = (const float*)d_in[9];
    const float* blk_conv_w = (const float*)d_in[10];
    const float* blk_conv_b = (const float*)d_in[11];
    const float* blk_A_log  = (const float*)d_in[12];
    const float* blk_D      = (const float*)d_in[13];
    const float* blk_dt_bias= (const float*)d_in[14];
    const float* blk_post_norm_w = (const float*)d_in[15];
    const float* blk_out_w  = (const float*)d_in[16];
    const float* blk_out_b  = (const float*)d_in[17];
    const float* out_norm_w = (const float*)d_in[18];

    float* out_deter = (float*)d_out;
    float* out_cs    = out_deter + (size_t)B_SZ * DETER;
    float* out_ss    = out_cs + (size_t)2 * B_SZ * CONV_DIM * 3;

    char* ws = (char*)d_ws;
    __bf16* Wb_inproj = (__bf16*)ws;  ws += (size_t)TOKEN_DIM * KIN * 2;
    __bf16* Wb_blkin  = (__bf16*)ws;  ws += (size_t)2 * IPP2 * TOKEN_DIM * 2;
    __bf16* Wb_blkout = (__bf16*)ws;  ws += (size_t)2 * TOKEN_DIM * HIDDEN * 2;
    float*  X         = (float*)ws;   ws += (size_t)B_SZ * TOKEN_DIM * 4;
    __bf16* Hb        = (__bf16*)ws;  ws += (size_t)B_SZ * TOKEN_DIM * 2;
    __bf16* PROJ      = (__bf16*)ws;  ws += (size_t)B_SZ * IPP2 * 2;    // bf16 now
    __bf16* Gb        = (__bf16*)ws;  ws += (size_t)B_SZ * HIDDEN * 2;
    float*  PART      = (float*)ws;   ws += (size_t)4 * B_SZ * TOKEN_DIM * 4;
    __bf16* INPb = PROJ;   // alias: consumed by input GEMM before PROJ written (2.2MB <= 4.6MB)

    // 0. weights -> bf16 (padded) + input row build (one kernel)
    {
        int total = N0C + N1C + N2C + N3C;
        prep_all<<<(total + 255) / 256, 256, 0, stream>>>(
            in_proj_w, blk_in_w, blk_out_w, stoch, action,
            Wb_inproj, Wb_blkin, Wb_blkout, INPb);
    }
    // 1. input GEMM (split-K 4: 17 steps -> 5,5,5,2) + fused reduce/rms/silu/rms
    {
        dim3 grid(TOKEN_DIM / 64, B_SZ / 128, 4);
        gemm_v2<true, float><<<grid, 256, 0, stream>>>(INPb, Wb_inproj, nullptr, PART,
                                                       B_SZ, TOKEN_DIM, KIN, 5);
        reduce_in_kernel<<<B_SZ, 256, 0, stream>>>(PART, in_proj_b, in_norm_w,
                                                   blk_norm_w, X, Hb);
    }

    for (int l = 0; l < 2; ++l) {
        const __bf16* iw = Wb_blkin + (size_t)l * IPP2 * TOKEN_DIM;
        const float* cw  = blk_conv_w + (size_t)l * CONV_DIM * 4;
        const float* cbv = blk_conv_b + (size_t)l * CONV_DIM;
        const float* alog= blk_A_log + (size_t)l * NHEADS;
        const float* Dvv = blk_D + (size_t)l * NHEADS;
        const float* dtb = blk_dt_bias + (size_t)l * NHEADS;
        const float* pw  = blk_post_norm_w + (size_t)l * HIDDEN;
        const __bf16* ow = Wb_blkout + (size_t)l * TOKEN_DIM * HIDDEN;
        const float* ob  = blk_out_b + (size_t)l * TOKEN_DIM;
        const float* cs_in = conv_state + (size_t)l * B_SZ * CONV_DIM * 3;
        const float* ss_in = ssm_state + (size_t)l * B_SZ * NHEADS * HEADDIM * DSTATE;
        float* cs_out = out_cs + (size_t)l * B_SZ * CONV_DIM * 3;
        float* ss_out = out_ss + (size_t)l * B_SZ * NHEADS * HEADDIM * DSTATE;

        // in-proj GEMM (no split): N=2304, bf16 out
        {
            dim3 grid(IPP2 / 64, B_SZ / 128);
            gemm_v2<false, __bf16><<<grid, 256, 0, stream>>>(Hb, iw, nullptr, PROJ,
                                                             B_SZ, IPP2, TOKEN_DIM, 0);
        }
        // fused conv + ssm + gate-rmsnorm
        conv_ssm_gate_kernel<<<B_SZ, 256, 0, stream>>>(
            cs_in, PROJ, cw, cbv, dtb, alog, Dvv, pw, ss_in, cs_out, ss_out, Gb);
        // out GEMM (split-K 4: 16 steps -> 4 each)
        {
            dim3 grid(TOKEN_DIM / 64, B_SZ / 128, 4);
            gemm_v2<true, float><<<grid, 256, 0, stream>>>(Gb, ow, nullptr, PART,
                                                           B_SZ, TOKEN_DIM, HIDDEN, 4);
        }
        // fused residual + rms (next layer or final tape)
        if (l == 0) {
            reduce_out_kernel<0><<<B_SZ, 256, 0, stream>>>(
                PART, ob, X, blk_norm_w + TOKEN_DIM, X, Hb, nullptr, nullptr);
        } else {
            reduce_out_kernel<1><<<B_SZ, 256, 0, stream>>>(
                PART, ob, X, out_norm_w, nullptr, nullptr, deter, out_deter);
        }
    }
}

// Round 6
// 283.916 us; speedup vs baseline: 2.6866x; 1.0568x over previous
//
#include <hip/hip_runtime.h>
#include <hip/hip_bf16.h>
#include <math.h>

#define B_SZ 1024
#define STOCH 1024
#define ACT 32
#define DETER 4096
#define TOKEN_DIM 512
#define HIDDEN 1024
#define NHEADS 8
#define HEADDIM 128
#define DSTATE 64
#define CONV_DIM 1152
#define IN_PROJ_DIM 2184
#define IPP2 2304         // in_proj N padded to 36*64
#define KIN 1088          // input GEMM K padded to 17*64
#define EPS 0.0001f

typedef float f32x4 __attribute__((ext_vector_type(4)));
typedef __bf16 bf16x8 __attribute__((ext_vector_type(8)));
typedef __bf16 bf16x4 __attribute__((ext_vector_type(4)));

// ---------------- fused prep: weights -> bf16 (padded) + input row build ----------------
#define N0C (512 * KIN / 4)
#define N1C (2 * IPP2 * TOKEN_DIM / 4)
#define N2C (2 * TOKEN_DIM * HIDDEN / 4)
#define N3C (B_SZ * KIN / 4)
__global__ __launch_bounds__(256) void prep_all(
    const float* __restrict__ inproj, const float* __restrict__ blkin,
    const float* __restrict__ blkout,
    const float* __restrict__ stoch, const float* __restrict__ action,
    __bf16* __restrict__ w0, __bf16* __restrict__ w1, __bf16* __restrict__ w2,
    __bf16* __restrict__ inp)
{
    int i = blockIdx.x * 256 + threadIdx.x;
    bf16x4 o = { (__bf16)0.f, (__bf16)0.f, (__bf16)0.f, (__bf16)0.f };
    if (i < N0C) {
        int idx = i * 4;
        int rr = idx / KIN, cc = idx % KIN;
        if (cc < STOCH + ACT) {
            float4 v = *(const float4*)(inproj + (size_t)rr * (STOCH + ACT) + cc);
            o = bf16x4{ (__bf16)v.x, (__bf16)v.y, (__bf16)v.z, (__bf16)v.w };
        }
        ((bf16x4*)w0)[i] = o;
    } else if (i < N0C + N1C) {
        int j = i - N0C;
        int idx = j * 4;
        int li  = idx / (IPP2 * TOKEN_DIM);
        int rem = idx % (IPP2 * TOKEN_DIM);
        int rr  = rem / TOKEN_DIM, cc = rem % TOKEN_DIM;
        if (rr < IN_PROJ_DIM) {
            float4 v = *(const float4*)(blkin + ((size_t)li * IN_PROJ_DIM + rr) * TOKEN_DIM + cc);
            o = bf16x4{ (__bf16)v.x, (__bf16)v.y, (__bf16)v.z, (__bf16)v.w };
        }
        ((bf16x4*)w1)[j] = o;
    } else if (i < N0C + N1C + N2C) {
        int j = i - N0C - N1C;
        float4 v = ((const float4*)blkout)[j];
        o = bf16x4{ (__bf16)v.x, (__bf16)v.y, (__bf16)v.z, (__bf16)v.w };
        ((bf16x4*)w2)[j] = o;
    } else if (i < N0C + N1C + N2C + N3C) {
        int j = i - N0C - N1C - N2C;
        int idx = j * 4;
        int b = idx / KIN, c = idx % KIN;
        if (c < STOCH) {
            float4 v = *(const float4*)(stoch + (size_t)b * STOCH + c);
            o = bf16x4{ (__bf16)v.x, (__bf16)v.y, (__bf16)v.z, (__bf16)v.w };
        } else if (c < STOCH + ACT) {
            float4 v = *(const float4*)(action + (size_t)b * ACT + (c - STOCH));
            float4 m;
            m.x = fabsf(v.x) > 1.f ? fabsf(v.x) : 1.f;
            m.y = fabsf(v.y) > 1.f ? fabsf(v.y) : 1.f;
            m.z = fabsf(v.z) > 1.f ? fabsf(v.z) : 1.f;
            m.w = fabsf(v.w) > 1.f ? fabsf(v.w) : 1.f;
            o = bf16x4{ (__bf16)(v.x / m.x), (__bf16)(v.y / m.y),
                        (__bf16)(v.z / m.z), (__bf16)(v.w / m.w) };
        }
        ((bf16x4*)inp)[j] = o;
    }
}

// ---------------- GEMM v2: 128x64 wg tile, wave 32x64, optional split-K ----------
// C = A_bf16(MxK) @ W_bf16(NxK)^T   M%128==0, N%64==0, K%64==0
template<bool SPLIT, typename OutT>
__global__ __launch_bounds__(256) void gemm_v2(
    const __bf16* __restrict__ A,
    const __bf16* __restrict__ W,
    const float* __restrict__ bias,   // only used when !SPLIT (may be null)
    OutT* __restrict__ C,             // !SPLIT: MxN ; SPLIT: [z][M][N]
    int M, int N, int K, int chunk_steps)
{
    __shared__ __bf16 As[128 * 64];   // 128 rows x 128B, XOR-swizzled
    __shared__ __bf16 Ws[64 * 64];
    const int tid = threadIdx.x;
    const int bn = blockIdx.x * 64;
    const int bm = blockIdx.y * 128;
    const int nsteps = K >> 6;
    int s_begin = 0, s_end = nsteps;
    OutT* Cout = C;
    if (SPLIT) {
        int z = blockIdx.z;
        s_begin = z * chunk_steps;
        int se = s_begin + chunk_steps;
        s_end = se < nsteps ? se : nsteps;
        Cout = C + (size_t)z * M * N;
    }

    const int wid = tid >> 6;
    const int lane = tid & 63;
    const int wr = wid * 32;
    const int r = lane & 15;
    const int kb = (lane >> 4) * 16;

    const int row0 = tid >> 3;
    const int colb = (tid & 7) * 16;
    const int wof = row0 * 128 + (colb ^ ((row0 & 7) << 4));
    char* Asb = (char*)As;
    char* Wsb = (char*)Ws;

    const __bf16* gA = A + (size_t)(bm + row0) * K + (s_begin << 6) + (colb >> 1);
    const __bf16* gW = W + (size_t)(bn + row0) * K + (s_begin << 6) + (colb >> 1);
    const size_t aK32 = (size_t)32 * K;

    const int ar0 = wr + r;
    const int ar1 = wr + 16 + r;
    const int aswz = (ar0 & 7) << 4;
    const int bswz = (r & 7) << 4;

    f32x4 acc[2][4] = {};
    bf16x8 va0 = *(const bf16x8*)(gA);
    bf16x8 va1 = *(const bf16x8*)(gA + aK32);
    bf16x8 va2 = *(const bf16x8*)(gA + 2 * aK32);
    bf16x8 va3 = *(const bf16x8*)(gA + 3 * aK32);
    bf16x8 vw0 = *(const bf16x8*)(gW);
    bf16x8 vw1 = *(const bf16x8*)(gW + aK32);

    for (int s = s_begin; s < s_end; ++s) {
        __syncthreads();
        *(bf16x8*)(Asb + wof) = va0;
        *(bf16x8*)(Asb + wof + 32 * 128) = va1;
        *(bf16x8*)(Asb + wof + 64 * 128) = va2;
        *(bf16x8*)(Asb + wof + 96 * 128) = va3;
        *(bf16x8*)(Wsb + wof) = vw0;
        *(bf16x8*)(Wsb + wof + 32 * 128) = vw1;
        __syncthreads();
        if (s + 1 < s_end) {
            const int ko = (s + 1 - s_begin) << 6;
            va0 = *(const bf16x8*)(gA + ko);
            va1 = *(const bf16x8*)(gA + aK32 + ko);
            va2 = *(const bf16x8*)(gA + 2 * aK32 + ko);
            va3 = *(const bf16x8*)(gA + 3 * aK32 + ko);
            vw0 = *(const bf16x8*)(gW + ko);
            vw1 = *(const bf16x8*)(gW + aK32 + ko);
        }
        #pragma unroll
        for (int ks = 0; ks < 2; ++ks) {
            const int cb = ks * 64 + kb;
            bf16x8 a0 = *(const bf16x8*)(Asb + ar0 * 128 + (cb ^ aswz));
            bf16x8 a1 = *(const bf16x8*)(Asb + ar1 * 128 + (cb ^ aswz));
            bf16x8 b0 = *(const bf16x8*)(Wsb + r * 128 + (cb ^ bswz));
            bf16x8 b1 = *(const bf16x8*)(Wsb + (r + 16) * 128 + (cb ^ bswz));
            bf16x8 b2 = *(const bf16x8*)(Wsb + (r + 32) * 128 + (cb ^ bswz));
            bf16x8 b3 = *(const bf16x8*)(Wsb + (r + 48) * 128 + (cb ^ bswz));
            acc[0][0] = __builtin_amdgcn_mfma_f32_16x16x32_bf16(a0, b0, acc[0][0], 0, 0, 0);
            acc[0][1] = __builtin_amdgcn_mfma_f32_16x16x32_bf16(a0, b1, acc[0][1], 0, 0, 0);
            acc[0][2] = __builtin_amdgcn_mfma_f32_16x16x32_bf16(a0, b2, acc[0][2], 0, 0, 0);
            acc[0][3] = __builtin_amdgcn_mfma_f32_16x16x32_bf16(a0, b3, acc[0][3], 0, 0, 0);
            acc[1][0] = __builtin_amdgcn_mfma_f32_16x16x32_bf16(a1, b0, acc[1][0], 0, 0, 0);
            acc[1][1] = __builtin_amdgcn_mfma_f32_16x16x32_bf16(a1, b1, acc[1][1], 0, 0, 0);
            acc[1][2] = __builtin_amdgcn_mfma_f32_16x16x32_bf16(a1, b2, acc[1][2], 0, 0, 0);
            acc[1][3] = __builtin_amdgcn_mfma_f32_16x16x32_bf16(a1, b3, acc[1][3], 0, 0, 0);
        }
    }

    const int cr = (lane >> 4) * 4;
    const int cc = lane & 15;
    #pragma unroll
    for (int mi = 0; mi < 2; mi++) {
        #pragma unroll
        for (int ni = 0; ni < 4; ni++) {
            int n = bn + ni * 16 + cc;
            #pragma unroll
            for (int j = 0; j < 4; j++) {
                int m = bm + wr + mi * 16 + cr + j;
                float v = acc[mi][ni][j];
                if (!SPLIT && bias) v += bias[n];
                Cout[(size_t)m * N + n] = (OutT)v;
            }
        }
    }
}

// ---------------- block-wide sum helper (256 threads) ----------------
__device__ __forceinline__ float block_sum(float v, float* red, int t) {
    #pragma unroll
    for (int off = 32; off >= 1; off >>= 1) v += __shfl_xor(v, off);
    if ((t & 63) == 0) red[t >> 6] = v;
    __syncthreads();
    float tot = red[0] + red[1] + red[2] + red[3];
    __syncthreads();
    return tot;
}

// ---------------- reduce_in: X = silu(rmsnorm(ΣP+bias, inw)); Hb = bf16(rmsnorm(X, nw)) ----
__global__ __launch_bounds__(256) void reduce_in_kernel(
    const float* __restrict__ P,      // [4][B][512]
    const float* __restrict__ bias,
    const float* __restrict__ inw,
    const float* __restrict__ nw,
    float* __restrict__ X, __bf16* __restrict__ Hb)
{
    __shared__ float red[4];
    int b = blockIdx.x, t = threadIdx.x;
    const size_t stride = (size_t)B_SZ * TOKEN_DIM;
    float h[2];
    float ss = 0.f;
    #pragma unroll
    for (int i = 0; i < 2; i++) {
        int c = t + i * 256;
        size_t o = (size_t)b * TOKEN_DIM + c;
        float v = P[o] + P[o + stride] + P[o + 2 * stride] + P[o + 3 * stride] + bias[c];
        h[i] = v;
        ss += v * v;
    }
    float tot = block_sum(ss, red, t);
    float sc = rsqrtf(tot / (float)TOKEN_DIM + EPS);
    float ss2 = 0.f;
    #pragma unroll
    for (int i = 0; i < 2; i++) {
        int c = t + i * 256;
        float v = h[i] * sc * inw[c];
        v = v / (1.f + expf(-v));        // silu
        h[i] = v;
        X[(size_t)b * TOKEN_DIM + c] = v;
        ss2 += v * v;
    }
    float tot2 = block_sum(ss2, red, t);
    float sc2 = rsqrtf(tot2 / (float)TOKEN_DIM + EPS);
    #pragma unroll
    for (int i = 0; i < 2; i++) {
        int c = t + i * 256;
        Hb[(size_t)b * TOKEN_DIM + c] = (__bf16)(h[i] * sc2 * nw[c]);
    }
}

// ---------------- reduce_out: newX = X + ΣP + ob; MODE0: X,Hb=rms(newX,w); MODE1: final tape ----
template<int MODE>
__global__ __launch_bounds__(256) void reduce_out_kernel(
    const float* __restrict__ P,      // [4][B][512]
    const float* __restrict__ ob,
    const float* __restrict__ Xin,
    const float* __restrict__ w,
    float* __restrict__ X,
    __bf16* __restrict__ Hb,
    const float* __restrict__ deter,
    float* __restrict__ out)
{
    __shared__ float red[4];
    int b = blockIdx.x, t = threadIdx.x;
    const size_t stride = (size_t)B_SZ * TOKEN_DIM;
    float h[2];
    float ss = 0.f;
    #pragma unroll
    for (int i = 0; i < 2; i++) {
        int c = t + i * 256;
        size_t o = (size_t)b * TOKEN_DIM + c;
        float v = Xin[o] + P[o] + P[o + stride] + P[o + 2 * stride] + P[o + 3 * stride] + ob[c];
        h[i] = v;
        ss += v * v;
    }
    float tot = block_sum(ss, red, t);
    float sc = rsqrtf(tot / (float)TOKEN_DIM + EPS);
    if (MODE == 0) {
        #pragma unroll
        for (int i = 0; i < 2; i++) {
            int c = t + i * 256;
            size_t o = (size_t)b * TOKEN_DIM + c;
            X[o] = h[i];
            Hb[o] = (__bf16)(h[i] * sc * w[c]);
        }
    } else {
        #pragma unroll
        for (int i = 0; i < 2; i++) {
            int c = t + i * 256;
            out[(size_t)b * DETER + 3584 + c] = h[i] * sc * w[c];
        }
        const float4* src = (const float4*)(deter + (size_t)b * DETER + TOKEN_DIM);
        float4* dst = (float4*)(out + (size_t)b * DETER);
        #pragma unroll
        for (int j = 0; j < 4; ++j) {
            int idx = t + j * 256;
            if (idx < 896) dst[idx] = src[idx];
        }
    }
}

// ---------------- fused conv + ssm + gate-rmsnorm (one block per batch row) ----------------
// v3: perfect 1KB/instruction coalescing (16 lanes per 256B state row, 4 rows/wave/instr),
//     8-row load batch per head (8KB in flight per wave), nontemporal stream.
__global__ __launch_bounds__(256, 4) void conv_ssm_gate_kernel(
    const float* __restrict__ cs,      // B x CONV_DIM x 3
    const __bf16* __restrict__ proj,   // B x IPP2 (bf16)
    const float* __restrict__ cw,      // CONV_DIM x 4
    const float* __restrict__ cb,      // CONV_DIM
    const float* __restrict__ dtb,     // NHEADS
    const float* __restrict__ alog,    // NHEADS
    const float* __restrict__ Dv,      // NHEADS
    const float* __restrict__ pw,      // HIDDEN
    const float* __restrict__ ss,      // B x NHEADS x HEADDIM x DSTATE
    float* __restrict__ new_cs,
    float* __restrict__ new_ss,
    __bf16* __restrict__ Gb)           // B x HIDDEN
{
    __shared__ float convs[CONV_DIM];  // x(1024) | B(64) | C(64)
    __shared__ float yrow[HIDDEN];
    __shared__ float dts[NHEADS], dAs[NHEADS], dvs[NHEADS];
    __shared__ float red[4];

    int b = blockIdx.x, t = threadIdx.x;
    const __bf16* prow = proj + (size_t)b * IPP2;

    if (t < NHEADS) {
        float dtr = (float)prow[HIDDEN + CONV_DIM + t] + dtb[t];
        float dt = dtr > 20.f ? dtr : log1pf(expf(dtr));
        dts[t] = dt;
        dAs[t] = expf(dt * -expf(alog[t]));
        dvs[t] = Dv[t];
    }
    // conv over 1152 channels
    for (int c = t; c < CONV_DIM; c += 256) {
        const float* s = cs + ((size_t)b * CONV_DIM + c) * 3;
        float s0 = s[0], s1 = s[1], s2 = s[2];
        float xbc = (float)prow[HIDDEN + c];
        float4 wv = *(const float4*)(cw + c * 4);
        float v = wv.x * s0 + wv.y * s1 + wv.z * s2 + wv.w * xbc + cb[c];
        v = v / (1.f + expf(-v));
        convs[c] = v;
        float* nc = new_cs + ((size_t)b * CONV_DIM + c) * 3;
        nc[0] = s1; nc[1] = s2; nc[2] = xbc;
    }
    __syncthreads();

    // SSM: 16 lanes cover one 256B state row; wave instruction = 1KB contiguous.
    const int p0 = t >> 4;            // 0..15
    const int nq = (t & 15) * 4;      // 0..60
    const f32x4 Bv = *(const f32x4*)&convs[HIDDEN + nq];
    const f32x4 Cv = *(const f32x4*)&convs[HIDDEN + DSTATE + nq];
    const float* basep = ss + (size_t)b * NHEADS * HEADDIM * DSTATE;
    float* baseo = new_ss + (size_t)b * NHEADS * HEADDIM * DSTATE;

    for (int h = 0; h < NHEADS; ++h) {
        const float dt = dts[h], dA = dAs[h], Dk = dvs[h];
        const float* sp = basep + (size_t)h * HEADDIM * DSTATE;
        float* op = baseo + (size_t)h * HEADDIM * DSTATE;
        f32x4 s4[8];
        #pragma unroll
        for (int it = 0; it < 8; ++it) {
            int p = it * 16 + p0;
            s4[it] = __builtin_nontemporal_load((const f32x4*)(sp + (size_t)p * DSTATE + nq));
        }
        #pragma unroll
        for (int it = 0; it < 8; ++it) {
            int p = it * 16 + p0;
            float xp = convs[h * HEADDIM + p];
            float dtx = dt * xp;
            f32x4 o = s4[it] * dA + dtx * Bv;
            __builtin_nontemporal_store(o, (f32x4*)(op + (size_t)p * DSTATE + nq));
            f32x4 a4 = o * Cv;
            float acc = (a4[0] + a4[1]) + (a4[2] + a4[3]);
            acc += __shfl_xor(acc, 1);
            acc += __shfl_xor(acc, 2);
            acc += __shfl_xor(acc, 4);
            acc += __shfl_xor(acc, 8);
            if ((t & 15) == 0) yrow[h * HEADDIM + p] = acc + Dk * xp;
        }
    }
    __syncthreads();

    // gate + rmsnorm over HIDDEN
    float vv[4];
    float ssum = 0.f;
    #pragma unroll
    for (int i = 0; i < 4; i++) {
        int j = t + i * 256;
        float z = (float)prow[j];
        float val = yrow[j] * (z / (1.f + expf(-z)));
        vv[i] = val;
        ssum += val * val;
    }
    float tot = block_sum(ssum, red, t);
    float sc = rsqrtf(tot / (float)HIDDEN + EPS);
    #pragma unroll
    for (int i = 0; i < 4; i++) {
        int j = t + i * 256;
        Gb[(size_t)b * HIDDEN + j] = (__bf16)(vv[i] * sc * pw[j]);
    }
}

// ---------------- launch ----------------
extern "C" void kernel_launch(void* const* d_in, const int* in_sizes, int n_in,
                              void* d_out, int out_size, void* d_ws, size_t ws_size,
                              hipStream_t stream) {
    const float* stoch      = (const float*)d_in[0];
    const float* deter      = (const float*)d_in[1];
    const float* action     = (const float*)d_in[2];
    const float* conv_state = (const float*)d_in[3];
    const float* ssm_state  = (const float*)d_in[4];
    const float* in_proj_w  = (const float*)d_in[5];
    const float* in_proj_b  = (const float*)d_in[6];
    const float* in_norm_w  = (const float*)d_in[7];
    const float* blk_norm_w = (const float*)d_in[8];
    const float* blk_in_w   = (const float*)d_in[9];
    const float* blk_conv_w = (const float*)d_in[10];
    const float* blk_conv_b = (const float*)d_in[11];
    const float* blk_A_log  = (const float*)d_in[12];
    const float* blk_D      = (const float*)d_in[13];
    const float* blk_dt_bias= (const float*)d_in[14];
    const float* blk_post_norm_w = (const float*)d_in[15];
    const float* blk_out_w  = (const float*)d_in[16];
    const float* blk_out_b  = (const float*)d_in[17];
    const float* out_norm_w = (const float*)d_in[18];

    float* out_deter = (float*)d_out;
    float* out_cs    = out_deter + (size_t)B_SZ * DETER;
    float* out_ss    = out_cs + (size_t)2 * B_SZ * CONV_DIM * 3;

    char* ws = (char*)d_ws;
    __bf16* Wb_inproj = (__bf16*)ws;  ws += (size_t)TOKEN_DIM * KIN * 2;
    __bf16* Wb_blkin  = (__bf16*)ws;  ws += (size_t)2 * IPP2 * TOKEN_DIM * 2;
    __bf16* Wb_blkout = (__bf16*)ws;  ws += (size_t)2 * TOKEN_DIM * HIDDEN * 2;
    float*  X         = (float*)ws;   ws += (size_t)B_SZ * TOKEN_DIM * 4;
    __bf16* Hb        = (__bf16*)ws;  ws += (size_t)B_SZ * TOKEN_DIM * 2;
    __bf16* PROJ      = (__bf16*)ws;  ws += (size_t)B_SZ * IPP2 * 2;    // bf16
    __bf16* Gb        = (__bf16*)ws;  ws += (size_t)B_SZ * HIDDEN * 2;
    float*  PART      = (float*)ws;   ws += (size_t)4 * B_SZ * TOKEN_DIM * 4;
    __bf16* INPb = PROJ;   // alias: consumed by input GEMM before PROJ written

    // 0. weights -> bf16 (padded) + input row build (one kernel)
    {
        int total = N0C + N1C + N2C + N3C;
        prep_all<<<(total + 255) / 256, 256, 0, stream>>>(
            in_proj_w, blk_in_w, blk_out_w, stoch, action,
            Wb_inproj, Wb_blkin, Wb_blkout, INPb);
    }
    // 1. input GEMM (split-K 4: 17 steps -> 5,5,5,2) + fused reduce/rms/silu/rms
    {
        dim3 grid(TOKEN_DIM / 64, B_SZ / 128, 4);
        gemm_v2<true, float><<<grid, 256, 0, stream>>>(INPb, Wb_inproj, nullptr, PART,
                                                       B_SZ, TOKEN_DIM, KIN, 5);
        reduce_in_kernel<<<B_SZ, 256, 0, stream>>>(PART, in_proj_b, in_norm_w,
                                                   blk_norm_w, X, Hb);
    }

    for (int l = 0; l < 2; ++l) {
        const __bf16* iw = Wb_blkin + (size_t)l * IPP2 * TOKEN_DIM;
        const float* cw  = blk_conv_w + (size_t)l * CONV_DIM * 4;
        const float* cbv = blk_conv_b + (size_t)l * CONV_DIM;
        const float* alog= blk_A_log + (size_t)l * NHEADS;
        const float* Dvv = blk_D + (size_t)l * NHEADS;
        const float* dtb = blk_dt_bias + (size_t)l * NHEADS;
        const float* pw  = blk_post_norm_w + (size_t)l * HIDDEN;
        const __bf16* ow = Wb_blkout + (size_t)l * TOKEN_DIM * HIDDEN;
        const float* ob  = blk_out_b + (size_t)l * TOKEN_DIM;
        const float* cs_in = conv_state + (size_t)l * B_SZ * CONV_DIM * 3;
        const float* ss_in = ssm_state + (size_t)l * B_SZ * NHEADS * HEADDIM * DSTATE;
        float* cs_out = out_cs + (size_t)l * B_SZ * CONV_DIM * 3;
        float* ss_out = out_ss + (size_t)l * B_SZ * NHEADS * HEADDIM * DSTATE;

        // in-proj GEMM (no split): N=2304, bf16 out
        {
            dim3 grid(IPP2 / 64, B_SZ / 128);
            gemm_v2<false, __bf16><<<grid, 256, 0, stream>>>(Hb, iw, nullptr, PROJ,
                                                             B_SZ, IPP2, TOKEN_DIM, 0);
        }
        // fused conv + ssm + gate-rmsnorm
        conv_ssm_gate_kernel<<<B_SZ, 256, 0, stream>>>(
            cs_in, PROJ, cw, cbv, dtb, alog, Dvv, pw, ss_in, cs_out, ss_out, Gb);
        // out GEMM (split-K 4: 16 steps -> 4 each)
        {
            dim3 grid(TOKEN_DIM / 64, B_SZ / 128, 4);
            gemm_v2<true, float><<<grid, 256, 0, stream>>>(Gb, ow, nullptr, PART,
                                                           B_SZ, TOKEN_DIM, HIDDEN, 4);
        }
        // fused residual + rms (next layer or final tape)
        if (l == 0) {
            reduce_out_kernel<0><<<B_SZ, 256, 0, stream>>>(
                PART, ob, X, blk_norm_w + TOKEN_DIM, X, Hb, nullptr, nullptr);
        } else {
            reduce_out_kernel<1><<<B_SZ, 256, 0, stream>>>(
                PART, ob, X, out_norm_w, nullptr, nullptr, deter, out_deter);
        }
    }
}

// Round 7
// 279.150 us; speedup vs baseline: 2.7325x; 1.0171x over previous
//
#include <hip/hip_runtime.h>
#include <hip/hip_bf16.h>
#include <math.h>

#define B_SZ 1024
#define STOCH 1024
#define ACT 32
#define DETER 4096
#define TOKEN_DIM 512
#define HIDDEN 1024
#define NHEADS 8
#define HEADDIM 128
#define DSTATE 64
#define CONV_DIM 1152
#define IN_PROJ_DIM 2184
#define IPP2 2304         // in_proj N padded to 36*64
#define KIN 1088          // input GEMM K padded to 17*64
#define EPS 0.0001f

typedef float f32x4 __attribute__((ext_vector_type(4)));
typedef __bf16 bf16x8 __attribute__((ext_vector_type(8)));
typedef __bf16 bf16x4 __attribute__((ext_vector_type(4)));

// ---------------- fused prep: weights -> bf16 (padded) + input row build ----------------
#define N0C (512 * KIN / 4)
#define N1C (2 * IPP2 * TOKEN_DIM / 4)
#define N2C (2 * TOKEN_DIM * HIDDEN / 4)
#define N3C (B_SZ * KIN / 4)
__global__ __launch_bounds__(256) void prep_all(
    const float* __restrict__ inproj, const float* __restrict__ blkin,
    const float* __restrict__ blkout,
    const float* __restrict__ stoch, const float* __restrict__ action,
    __bf16* __restrict__ w0, __bf16* __restrict__ w1, __bf16* __restrict__ w2,
    __bf16* __restrict__ inp)
{
    int i = blockIdx.x * 256 + threadIdx.x;
    bf16x4 o = { (__bf16)0.f, (__bf16)0.f, (__bf16)0.f, (__bf16)0.f };
    if (i < N0C) {
        int idx = i * 4;
        int rr = idx / KIN, cc = idx % KIN;
        if (cc < STOCH + ACT) {
            float4 v = *(const float4*)(inproj + (size_t)rr * (STOCH + ACT) + cc);
            o = bf16x4{ (__bf16)v.x, (__bf16)v.y, (__bf16)v.z, (__bf16)v.w };
        }
        ((bf16x4*)w0)[i] = o;
    } else if (i < N0C + N1C) {
        int j = i - N0C;
        int idx = j * 4;
        int li  = idx / (IPP2 * TOKEN_DIM);
        int rem = idx % (IPP2 * TOKEN_DIM);
        int rr  = rem / TOKEN_DIM, cc = rem % TOKEN_DIM;
        if (rr < IN_PROJ_DIM) {
            float4 v = *(const float4*)(blkin + ((size_t)li * IN_PROJ_DIM + rr) * TOKEN_DIM + cc);
            o = bf16x4{ (__bf16)v.x, (__bf16)v.y, (__bf16)v.z, (__bf16)v.w };
        }
        ((bf16x4*)w1)[j] = o;
    } else if (i < N0C + N1C + N2C) {
        int j = i - N0C - N1C;
        float4 v = ((const float4*)blkout)[j];
        o = bf16x4{ (__bf16)v.x, (__bf16)v.y, (__bf16)v.z, (__bf16)v.w };
        ((bf16x4*)w2)[j] = o;
    } else if (i < N0C + N1C + N2C + N3C) {
        int j = i - N0C - N1C - N2C;
        int idx = j * 4;
        int b = idx / KIN, c = idx % KIN;
        if (c < STOCH) {
            float4 v = *(const float4*)(stoch + (size_t)b * STOCH + c);
            o = bf16x4{ (__bf16)v.x, (__bf16)v.y, (__bf16)v.z, (__bf16)v.w };
        } else if (c < STOCH + ACT) {
            float4 v = *(const float4*)(action + (size_t)b * ACT + (c - STOCH));
            float4 m;
            m.x = fabsf(v.x) > 1.f ? fabsf(v.x) : 1.f;
            m.y = fabsf(v.y) > 1.f ? fabsf(v.y) : 1.f;
            m.z = fabsf(v.z) > 1.f ? fabsf(v.z) : 1.f;
            m.w = fabsf(v.w) > 1.f ? fabsf(v.w) : 1.f;
            o = bf16x4{ (__bf16)(v.x / m.x), (__bf16)(v.y / m.y),
                        (__bf16)(v.z / m.z), (__bf16)(v.w / m.w) };
        }
        ((bf16x4*)inp)[j] = o;
    }
}

// ---------------- GEMM v2: 128x64 wg tile, wave 32x64, optional split-K ----------
// C = A_bf16(MxK) @ W_bf16(NxK)^T   M%128==0, N%64==0, K%64==0
template<bool SPLIT, typename OutT>
__global__ __launch_bounds__(256) void gemm_v2(
    const __bf16* __restrict__ A,
    const __bf16* __restrict__ W,
    const float* __restrict__ bias,   // only used when !SPLIT (may be null)
    OutT* __restrict__ C,             // !SPLIT: MxN ; SPLIT: [z][M][N]
    int M, int N, int K, int chunk_steps)
{
    __shared__ __bf16 As[128 * 64];   // 128 rows x 128B, XOR-swizzled
    __shared__ __bf16 Ws[64 * 64];
    const int tid = threadIdx.x;
    const int bn = blockIdx.x * 64;
    const int bm = blockIdx.y * 128;
    const int nsteps = K >> 6;
    int s_begin = 0, s_end = nsteps;
    OutT* Cout = C;
    if (SPLIT) {
        int z = blockIdx.z;
        s_begin = z * chunk_steps;
        int se = s_begin + chunk_steps;
        s_end = se < nsteps ? se : nsteps;
        Cout = C + (size_t)z * M * N;
    }

    const int wid = tid >> 6;
    const int lane = tid & 63;
    const int wr = wid * 32;
    const int r = lane & 15;
    const int kb = (lane >> 4) * 16;

    const int row0 = tid >> 3;
    const int colb = (tid & 7) * 16;
    const int wof = row0 * 128 + (colb ^ ((row0 & 7) << 4));
    char* Asb = (char*)As;
    char* Wsb = (char*)Ws;

    const __bf16* gA = A + (size_t)(bm + row0) * K + (s_begin << 6) + (colb >> 1);
    const __bf16* gW = W + (size_t)(bn + row0) * K + (s_begin << 6) + (colb >> 1);
    const size_t aK32 = (size_t)32 * K;

    const int ar0 = wr + r;
    const int ar1 = wr + 16 + r;
    const int aswz = (ar0 & 7) << 4;
    const int bswz = (r & 7) << 4;

    f32x4 acc[2][4] = {};
    bf16x8 va0 = *(const bf16x8*)(gA);
    bf16x8 va1 = *(const bf16x8*)(gA + aK32);
    bf16x8 va2 = *(const bf16x8*)(gA + 2 * aK32);
    bf16x8 va3 = *(const bf16x8*)(gA + 3 * aK32);
    bf16x8 vw0 = *(const bf16x8*)(gW);
    bf16x8 vw1 = *(const bf16x8*)(gW + aK32);

    for (int s = s_begin; s < s_end; ++s) {
        __syncthreads();
        *(bf16x8*)(Asb + wof) = va0;
        *(bf16x8*)(Asb + wof + 32 * 128) = va1;
        *(bf16x8*)(Asb + wof + 64 * 128) = va2;
        *(bf16x8*)(Asb + wof + 96 * 128) = va3;
        *(bf16x8*)(Wsb + wof) = vw0;
        *(bf16x8*)(Wsb + wof + 32 * 128) = vw1;
        __syncthreads();
        if (s + 1 < s_end) {
            const int ko = (s + 1 - s_begin) << 6;
            va0 = *(const bf16x8*)(gA + ko);
            va1 = *(const bf16x8*)(gA + aK32 + ko);
            va2 = *(const bf16x8*)(gA + 2 * aK32 + ko);
            va3 = *(const bf16x8*)(gA + 3 * aK32 + ko);
            vw0 = *(const bf16x8*)(gW + ko);
            vw1 = *(const bf16x8*)(gW + aK32 + ko);
        }
        #pragma unroll
        for (int ks = 0; ks < 2; ++ks) {
            const int cb = ks * 64 + kb;
            bf16x8 a0 = *(const bf16x8*)(Asb + ar0 * 128 + (cb ^ aswz));
            bf16x8 a1 = *(const bf16x8*)(Asb + ar1 * 128 + (cb ^ aswz));
            bf16x8 b0 = *(const bf16x8*)(Wsb + r * 128 + (cb ^ bswz));
            bf16x8 b1 = *(const bf16x8*)(Wsb + (r + 16) * 128 + (cb ^ bswz));
            bf16x8 b2 = *(const bf16x8*)(Wsb + (r + 32) * 128 + (cb ^ bswz));
            bf16x8 b3 = *(const bf16x8*)(Wsb + (r + 48) * 128 + (cb ^ bswz));
            acc[0][0] = __builtin_amdgcn_mfma_f32_16x16x32_bf16(a0, b0, acc[0][0], 0, 0, 0);
            acc[0][1] = __builtin_amdgcn_mfma_f32_16x16x32_bf16(a0, b1, acc[0][1], 0, 0, 0);
            acc[0][2] = __builtin_amdgcn_mfma_f32_16x16x32_bf16(a0, b2, acc[0][2], 0, 0, 0);
            acc[0][3] = __builtin_amdgcn_mfma_f32_16x16x32_bf16(a0, b3, acc[0][3], 0, 0, 0);
            acc[1][0] = __builtin_amdgcn_mfma_f32_16x16x32_bf16(a1, b0, acc[1][0], 0, 0, 0);
            acc[1][1] = __builtin_amdgcn_mfma_f32_16x16x32_bf16(a1, b1, acc[1][1], 0, 0, 0);
            acc[1][2] = __builtin_amdgcn_mfma_f32_16x16x32_bf16(a1, b2, acc[1][2], 0, 0, 0);
            acc[1][3] = __builtin_amdgcn_mfma_f32_16x16x32_bf16(a1, b3, acc[1][3], 0, 0, 0);
        }
    }

    const int cr = (lane >> 4) * 4;
    const int cc = lane & 15;
    #pragma unroll
    for (int mi = 0; mi < 2; mi++) {
        #pragma unroll
        for (int ni = 0; ni < 4; ni++) {
            int n = bn + ni * 16 + cc;
            #pragma unroll
            for (int j = 0; j < 4; j++) {
                int m = bm + wr + mi * 16 + cr + j;
                float v = acc[mi][ni][j];
                if (!SPLIT && bias) v += bias[n];
                Cout[(size_t)m * N + n] = (OutT)v;
            }
        }
    }
}

// ---------------- block-wide sum helper (256 threads) ----------------
__device__ __forceinline__ float block_sum(float v, float* red, int t) {
    #pragma unroll
    for (int off = 32; off >= 1; off >>= 1) v += __shfl_xor(v, off);
    if ((t & 63) == 0) red[t >> 6] = v;
    __syncthreads();
    float tot = red[0] + red[1] + red[2] + red[3];
    __syncthreads();
    return tot;
}

// ---------------- reduce_in: X = silu(rmsnorm(ΣP+bias, inw)); Hb = bf16(rmsnorm(X, nw)) ----
__global__ __launch_bounds__(256) void reduce_in_kernel(
    const float* __restrict__ P,      // [4][B][512]
    const float* __restrict__ bias,
    const float* __restrict__ inw,
    const float* __restrict__ nw,
    float* __restrict__ X, __bf16* __restrict__ Hb)
{
    __shared__ float red[4];
    int b = blockIdx.x, t = threadIdx.x;
    const size_t stride = (size_t)B_SZ * TOKEN_DIM;
    float h[2];
    float ss = 0.f;
    #pragma unroll
    for (int i = 0; i < 2; i++) {
        int c = t + i * 256;
        size_t o = (size_t)b * TOKEN_DIM + c;
        float v = P[o] + P[o + stride] + P[o + 2 * stride] + P[o + 3 * stride] + bias[c];
        h[i] = v;
        ss += v * v;
    }
    float tot = block_sum(ss, red, t);
    float sc = rsqrtf(tot / (float)TOKEN_DIM + EPS);
    float ss2 = 0.f;
    #pragma unroll
    for (int i = 0; i < 2; i++) {
        int c = t + i * 256;
        float v = h[i] * sc * inw[c];
        v = v / (1.f + expf(-v));        // silu
        h[i] = v;
        X[(size_t)b * TOKEN_DIM + c] = v;
        ss2 += v * v;
    }
    float tot2 = block_sum(ss2, red, t);
    float sc2 = rsqrtf(tot2 / (float)TOKEN_DIM + EPS);
    #pragma unroll
    for (int i = 0; i < 2; i++) {
        int c = t + i * 256;
        Hb[(size_t)b * TOKEN_DIM + c] = (__bf16)(h[i] * sc2 * nw[c]);
    }
}

// ---------------- reduce_out: newX = X + ΣP + ob; MODE0: X,Hb=rms(newX,w); MODE1: final tape ----
template<int MODE>
__global__ __launch_bounds__(256) void reduce_out_kernel(
    const float* __restrict__ P,      // [4][B][512]
    const float* __restrict__ ob,
    const float* __restrict__ Xin,
    const float* __restrict__ w,
    float* __restrict__ X,
    __bf16* __restrict__ Hb,
    const float* __restrict__ deter,
    float* __restrict__ out)
{
    __shared__ float red[4];
    int b = blockIdx.x, t = threadIdx.x;
    const size_t stride = (size_t)B_SZ * TOKEN_DIM;
    float h[2];
    float ss = 0.f;
    #pragma unroll
    for (int i = 0; i < 2; i++) {
        int c = t + i * 256;
        size_t o = (size_t)b * TOKEN_DIM + c;
        float v = Xin[o] + P[o] + P[o + stride] + P[o + 2 * stride] + P[o + 3 * stride] + ob[c];
        h[i] = v;
        ss += v * v;
    }
    float tot = block_sum(ss, red, t);
    float sc = rsqrtf(tot / (float)TOKEN_DIM + EPS);
    if (MODE == 0) {
        #pragma unroll
        for (int i = 0; i < 2; i++) {
            int c = t + i * 256;
            size_t o = (size_t)b * TOKEN_DIM + c;
            X[o] = h[i];
            Hb[o] = (__bf16)(h[i] * sc * w[c]);
        }
    } else {
        #pragma unroll
        for (int i = 0; i < 2; i++) {
            int c = t + i * 256;
            out[(size_t)b * DETER + 3584 + c] = h[i] * sc * w[c];
        }
        const float4* src = (const float4*)(deter + (size_t)b * DETER + TOKEN_DIM);
        float4* dst = (float4*)(out + (size_t)b * DETER);
        #pragma unroll
        for (int j = 0; j < 4; ++j) {
            int idx = t + j * 256;
            if (idx < 896) dst[idx] = src[idx];
        }
    }
}

// ---------------- fused conv + ssm + gate-rmsnorm (one block per batch row) ----------------
// v4: software-pipelined heads — head0 loads issued BEFORE conv phase (conv hides
//     their latency); head h+1's 8x1KB batch prefetched before computing head h
//     (full compile-time unroll, no register copies).
__global__ __launch_bounds__(256, 4) void conv_ssm_gate_kernel(
    const float* __restrict__ cs,      // B x CONV_DIM x 3
    const __bf16* __restrict__ proj,   // B x IPP2 (bf16)
    const float* __restrict__ cw,      // CONV_DIM x 4
    const float* __restrict__ cb,      // CONV_DIM
    const float* __restrict__ dtb,     // NHEADS
    const float* __restrict__ alog,    // NHEADS
    const float* __restrict__ Dv,      // NHEADS
    const float* __restrict__ pw,      // HIDDEN
    const float* __restrict__ ss,      // B x NHEADS x HEADDIM x DSTATE
    float* __restrict__ new_cs,
    float* __restrict__ new_ss,
    __bf16* __restrict__ Gb)           // B x HIDDEN
{
    __shared__ float convs[CONV_DIM];  // x(1024) | B(64) | C(64)
    __shared__ float yrow[HIDDEN];
    __shared__ float dts[NHEADS], dAs[NHEADS], dvs[NHEADS];
    __shared__ float red[4];

    int b = blockIdx.x, t = threadIdx.x;
    const __bf16* prow = proj + (size_t)b * IPP2;

    // SSM thread mapping: 16 lanes cover one 256B state row; wave instr = 1KB contiguous.
    const int p0 = t >> 4;            // 0..15
    const int nq = (t & 15) * 4;      // 0..60
    const float* basep = ss + (size_t)b * NHEADS * HEADDIM * DSTATE;
    float* baseo = new_ss + (size_t)b * NHEADS * HEADDIM * DSTATE;

    // prefetch head 0 state (in flight during conv phase)
    f32x4 cur[8], nxt[8];
    #pragma unroll
    for (int it = 0; it < 8; ++it) {
        int p = it * 16 + p0;
        cur[it] = __builtin_nontemporal_load((const f32x4*)(basep + (size_t)p * DSTATE + nq));
    }

    if (t < NHEADS) {
        float dtr = (float)prow[HIDDEN + CONV_DIM + t] + dtb[t];
        float dt = dtr > 20.f ? dtr : log1pf(expf(dtr));
        dts[t] = dt;
        dAs[t] = expf(dt * -expf(alog[t]));
        dvs[t] = Dv[t];
    }
    // conv over 1152 channels
    for (int c = t; c < CONV_DIM; c += 256) {
        const float* s = cs + ((size_t)b * CONV_DIM + c) * 3;
        float s0 = s[0], s1 = s[1], s2 = s[2];
        float xbc = (float)prow[HIDDEN + c];
        float4 wv = *(const float4*)(cw + c * 4);
        float v = wv.x * s0 + wv.y * s1 + wv.z * s2 + wv.w * xbc + cb[c];
        v = v / (1.f + expf(-v));
        convs[c] = v;
        float* nc = new_cs + ((size_t)b * CONV_DIM + c) * 3;
        nc[0] = s1; nc[1] = s2; nc[2] = xbc;
    }
    __syncthreads();

    const f32x4 Bv = *(const f32x4*)&convs[HIDDEN + nq];
    const f32x4 Cv = *(const f32x4*)&convs[HIDDEN + DSTATE + nq];

    #pragma unroll
    for (int h = 0; h < NHEADS; ++h) {
        // prefetch next head's batch before computing current head
        if (h + 1 < NHEADS) {
            #pragma unroll
            for (int it = 0; it < 8; ++it) {
                int p = it * 16 + p0;
                nxt[it] = __builtin_nontemporal_load(
                    (const f32x4*)(basep + (size_t)((h + 1) * HEADDIM + p) * DSTATE + nq));
            }
        }
        const float dt = dts[h], dA = dAs[h], Dk = dvs[h];
        float* op = baseo + (size_t)h * HEADDIM * DSTATE;
        #pragma unroll
        for (int it = 0; it < 8; ++it) {
            int p = it * 16 + p0;
            float xp = convs[h * HEADDIM + p];
            float dtx = dt * xp;
            f32x4 o = cur[it] * dA + dtx * Bv;
            __builtin_nontemporal_store(o, (f32x4*)(op + (size_t)p * DSTATE + nq));
            f32x4 a4 = o * Cv;
            float acc = (a4[0] + a4[1]) + (a4[2] + a4[3]);
            acc += __shfl_xor(acc, 1);
            acc += __shfl_xor(acc, 2);
            acc += __shfl_xor(acc, 4);
            acc += __shfl_xor(acc, 8);
            if ((t & 15) == 0) yrow[h * HEADDIM + p] = acc + Dk * xp;
        }
        if (h + 1 < NHEADS) {
            #pragma unroll
            for (int it = 0; it < 8; ++it) cur[it] = nxt[it];  // renamed away by unroll
        }
    }
    __syncthreads();

    // gate + rmsnorm over HIDDEN
    float vv[4];
    float ssum = 0.f;
    #pragma unroll
    for (int i = 0; i < 4; i++) {
        int j = t + i * 256;
        float z = (float)prow[j];
        float val = yrow[j] * (z / (1.f + expf(-z)));
        vv[i] = val;
        ssum += val * val;
    }
    float tot = block_sum(ssum, red, t);
    float sc = rsqrtf(tot / (float)HIDDEN + EPS);
    #pragma unroll
    for (int i = 0; i < 4; i++) {
        int j = t + i * 256;
        Gb[(size_t)b * HIDDEN + j] = (__bf16)(vv[i] * sc * pw[j]);
    }
}

// ---------------- launch ----------------
extern "C" void kernel_launch(void* const* d_in, const int* in_sizes, int n_in,
                              void* d_out, int out_size, void* d_ws, size_t ws_size,
                              hipStream_t stream) {
    const float* stoch      = (const float*)d_in[0];
    const float* deter      = (const float*)d_in[1];
    const float* action     = (const float*)d_in[2];
    const float* conv_state = (const float*)d_in[3];
    const float* ssm_state  = (const float*)d_in[4];
    const float* in_proj_w  = (const float*)d_in[5];
    const float* in_proj_b  = (const float*)d_in[6];
    const float* in_norm_w  = (const float*)d_in[7];
    const float* blk_norm_w = (const float*)d_in[8];
    const float* blk_in_w   = (const float*)d_in[9];
    const float* blk_conv_w = (const float*)d_in[10];
    const float* blk_conv_b = (const float*)d_in[11];
    const float* blk_A_log  = (const float*)d_in[12];
    const float* blk_D      = (const float*)d_in[13];
    const float* blk_dt_bias= (const float*)d_in[14];
    const float* blk_post_norm_w = (const float*)d_in[15];
    const float* blk_out_w  = (const float*)d_in[16];
    const float* blk_out_b  = (const float*)d_in[17];
    const float* out_norm_w = (const float*)d_in[18];

    float* out_deter = (float*)d_out;
    float* out_cs    = out_deter + (size_t)B_SZ * DETER;
    float* out_ss    = out_cs + (size_t)2 * B_SZ * CONV_DIM * 3;

    char* ws = (char*)d_ws;
    __bf16* Wb_inproj = (__bf16*)ws;  ws += (size_t)TOKEN_DIM * KIN * 2;
    __bf16* Wb_blkin  = (__bf16*)ws;  ws += (size_t)2 * IPP2 * TOKEN_DIM * 2;
    __bf16* Wb_blkout = (__bf16*)ws;  ws += (size_t)2 * TOKEN_DIM * HIDDEN * 2;
    float*  X         = (float*)ws;   ws += (size_t)B_SZ * TOKEN_DIM * 4;
    __bf16* Hb        = (__bf16*)ws;  ws += (size_t)B_SZ * TOKEN_DIM * 2;
    __bf16* PROJ      = (__bf16*)ws;  ws += (size_t)B_SZ * IPP2 * 2;    // bf16
    __bf16* Gb        = (__bf16*)ws;  ws += (size_t)B_SZ * HIDDEN * 2;
    float*  PART      = (float*)ws;   ws += (size_t)4 * B_SZ * TOKEN_DIM * 4;
    __bf16* INPb = PROJ;   // alias: consumed by input GEMM before PROJ written

    // 0. weights -> bf16 (padded) + input row build (one kernel)
    {
        int total = N0C + N1C + N2C + N3C;
        prep_all<<<(total + 255) / 256, 256, 0, stream>>>(
            in_proj_w, blk_in_w, blk_out_w, stoch, action,
            Wb_inproj, Wb_blkin, Wb_blkout, INPb);
    }
    // 1. input GEMM (split-K 4: 17 steps -> 5,5,5,2) + fused reduce/rms/silu/rms
    {
        dim3 grid(TOKEN_DIM / 64, B_SZ / 128, 4);
        gemm_v2<true, float><<<grid, 256, 0, stream>>>(INPb, Wb_inproj, nullptr, PART,
                                                       B_SZ, TOKEN_DIM, KIN, 5);
        reduce_in_kernel<<<B_SZ, 256, 0, stream>>>(PART, in_proj_b, in_norm_w,
                                                   blk_norm_w, X, Hb);
    }

    for (int l = 0; l < 2; ++l) {
        const __bf16* iw = Wb_blkin + (size_t)l * IPP2 * TOKEN_DIM;
        const float* cw  = blk_conv_w + (size_t)l * CONV_DIM * 4;
        const float* cbv = blk_conv_b + (size_t)l * CONV_DIM;
        const float* alog= blk_A_log + (size_t)l * NHEADS;
        const float* Dvv = blk_D + (size_t)l * NHEADS;
        const float* dtb = blk_dt_bias + (size_t)l * NHEADS;
        const float* pw  = blk_post_norm_w + (size_t)l * HIDDEN;
        const __bf16* ow = Wb_blkout + (size_t)l * TOKEN_DIM * HIDDEN;
        const float* ob  = blk_out_b + (size_t)l * TOKEN_DIM;
        const float* cs_in = conv_state + (size_t)l * B_SZ * CONV_DIM * 3;
        const float* ss_in = ssm_state + (size_t)l * B_SZ * NHEADS * HEADDIM * DSTATE;
        float* cs_out = out_cs + (size_t)l * B_SZ * CONV_DIM * 3;
        float* ss_out = out_ss + (size_t)l * B_SZ * NHEADS * HEADDIM * DSTATE;

        // in-proj GEMM (no split): N=2304, bf16 out
        {
            dim3 grid(IPP2 / 64, B_SZ / 128);
            gemm_v2<false, __bf16><<<grid, 256, 0, stream>>>(Hb, iw, nullptr, PROJ,
                                                             B_SZ, IPP2, TOKEN_DIM, 0);
        }
        // fused conv + ssm + gate-rmsnorm
        conv_ssm_gate_kernel<<<B_SZ, 256, 0, stream>>>(
            cs_in, PROJ, cw, cbv, dtb, alog, Dvv, pw, ss_in, cs_out, ss_out, Gb);
        // out GEMM (split-K 4: 16 steps -> 4 each)
        {
            dim3 grid(TOKEN_DIM / 64, B_SZ / 128, 4);
            gemm_v2<true, float><<<grid, 256, 0, stream>>>(Gb, ow, nullptr, PART,
                                                           B_SZ, TOKEN_DIM, HIDDEN, 4);
        }
        // fused residual + rms (next layer or final tape)
        if (l == 0) {
            reduce_out_kernel<0><<<B_SZ, 256, 0, stream>>>(
                PART, ob, X, blk_norm_w + TOKEN_DIM, X, Hb, nullptr, nullptr);
        } else {
            reduce_out_kernel<1><<<B_SZ, 256, 0, stream>>>(
                PART, ob, X, out_norm_w, nullptr, nullptr, deter, out_deter);
        }
    }
}